// Round 18
// baseline (225.760 us; speedup 1.0000x reference)
//
#include <hip/hip_runtime.h>

#define HEADS 8
#define DHEAD 64
#define QSCALE 0.125f        // 64^-0.5
#define QSCALE2 0.1803368801111204f  // QSCALE * log2(e): exp2-direct softmax
#define DIM 256
#define IMG 112
#define HW 12544        // 112*112
#define NKV 256         // 16*16
#define INNER 512
#define KCONV 12544     // 256*49
#define KSPLIT 8
#define KCHUNK 1568     // 12544/8
#define K2STEPS 49      // KCHUNK/32

typedef _Float16 half_t;
typedef _Float16 half8 __attribute__((ext_vector_type(8)));
typedef float f32x4 __attribute__((ext_vector_type(4)));

__device__ inline unsigned pk2(float a, float b) {
    union { half_t h[2]; unsigned u; } x;
    x.h[0] = (half_t)a; x.h[1] = (half_t)b;
    return x.u;
}

// ---------------- Kcvt-all: all three weight conversions in one launch.
// grid 6400: [0,6272) Wkv, [6272,6336) Wq (QSCALE2 folded), [6336,6400) Wout
__global__ __launch_bounds__(256) void k_cvtall(const float* __restrict__ Wkv,
                                                const float* __restrict__ Wq,
                                                const float* __restrict__ Wout,
                                                half_t* __restrict__ Wkv16,
                                                half_t* __restrict__ Wq16s,
                                                half_t* __restrict__ Wout16) {
    int bid = blockIdx.x;
    const float* W;
    half_t* W16;
    float scale;
    int OC, K, gid;
    if (bid < 6272) {
        W = Wkv; W16 = Wkv16; scale = 1.0f; OC = 1024; K = KCONV;
        gid = bid * 256 + threadIdx.x;
    } else if (bid < 6336) {
        W = Wq; W16 = Wq16s; scale = QSCALE2; OC = 512; K = DIM;
        gid = (bid - 6272) * 256 + threadIdx.x;
    } else {
        W = Wout; W16 = Wout16; scale = 1.0f; OC = 256; K = INNER;
        gid = (bid - 6336) * 256 + threadIdx.x;
    }
    int perRow = K >> 3;
    int oc = gid / perRow;
    int k0 = (gid - oc * perRow) * 8;
    const float* src = W + (size_t)oc * K + k0;
    float4 a = *(const float4*)src;
    float4 b = *(const float4*)(src + 4);
    half8 h = { (half_t)(a.x * scale), (half_t)(a.y * scale),
                (half_t)(a.z * scale), (half_t)(a.w * scale),
                (half_t)(b.x * scale), (half_t)(b.y * scale),
                (half_t)(b.z * scale), (half_t)(b.w * scale) };
    *(half8*)&W16[(((size_t)(k0 >> 5) * OC + oc) * 4 + ((k0 >> 3) & 3)) * 8] = h;
}

// ---------------- K_prep: single-pass x -> {Pt', x'} via LDS tile.
// Block = (oy strip, 32-channel group cg, batch b). 32ch x 49taps = 49 aligned kk-chunks.
// LDS: xs[32][786] f32 (7x112 rows + pad2) + tbl[1568] (klocal -> xs offset).
__global__ __launch_bounds__(256) void k_prep(const float* __restrict__ x,
                                              half_t* __restrict__ Pt,
                                              half_t* __restrict__ xT16) {
    extern __shared__ float xs[];            // 32*786 floats
    int* tbl = (int*)(xs + 32 * 786);        // 1568 ints
    int t = threadIdx.x;
    int oy = blockIdx.x, cg = blockIdx.y, b = blockIdx.z;
    int c0 = cg * 32;

    // k-offset table (ox-independent part of the gather address)
    for (int i = 0; i < 7; ++i) {
        int k = t + i * 256;
        if (k < 1568) {
            int ch = k / 49, tap = k - ch * 49;
            int kh = tap / 7, kw = tap - kh * 7;
            tbl[k] = ch * 786 + kh * 112 + kw;
        }
    }
    // load x tile coalesced: 32 ch x 7 rows x 112 cols (12544 float2)
    const float* xb = x + ((size_t)(b * DIM + c0) * IMG + oy * 7) * IMG;
    for (int j = 0; j < 49; ++j) {
        int idx = t + j * 256;
        int seg = idx / 56, within = idx - seg * 56;
        int ch = seg / 7, row = seg - ch * 7;
        float2 v = *(const float2*)&xb[((size_t)ch * IMG + row) * IMG + within * 2];
        *(float2*)&xs[ch * 786 + row * 112 + within * 2] = v;
    }
    __syncthreads();

    // emit Pt'[b][kk = cg*49+kkl][pos = oy*16+ox][32 halves]: wave stores 256B contiguous
    half_t* ptb = Pt + ((size_t)(b * 392 + cg * 49) * 256 + oy * 16) * 32;
    for (int j = 0; j < 49; ++j) {
        int p = t + j * 256;
        int row = p >> 4, pairIn = p & 15;
        int kkl = row >> 4, ox = row & 15;
        int kl = kkl * 32 + pairIn * 2;
        int o7 = ox * 7;
        unsigned u = pk2(xs[tbl[kl] + o7], xs[tbl[kl + 1] + o7]);
        *(unsigned*)&ptb[((size_t)kkl * 256 + ox) * 32 + pairIn * 2] = u;
    }
    // emit x'[b][cg][n = oy*784 + pi][32 halves]: wave stores 256B contiguous
    half_t* xtb = xT16 + ((size_t)(b * 8 + cg) * HW + (size_t)(oy * 7) * IMG) * 32;
    for (int j = 0; j < 49; ++j) {
        int p = t + j * 256;
        int pi = p >> 4, pairIn = p & 15;
        int cl = pairIn * 2;
        unsigned u = pk2(xs[cl * 786 + pi], xs[(cl + 1) * 786 + pi]);
        *(unsigned*)&xtb[(size_t)pi * 32 + pairIn * 2] = u;
    }
}

// ---------------- K1: Q projection, m97 template: 128x128 tile, gload_lds dbuf, K=256
__global__ __launch_bounds__(256) void k1_qproj(const half_t* __restrict__ Wq16s,
                                                const half_t* __restrict__ xT16,
                                                half_t* __restrict__ qtok) {
    __shared__ half_t As[2][128 * 32];
    __shared__ half_t Bs[2][128 * 32];
    int t = threadIdx.x;
    int w = t >> 6, l = t & 63, g = l >> 4, c = l & 15;
    int bid = blockIdx.x;                       // grid 1568 = 8 * 196
    int logical = (bid & 7) * 196 + (bid >> 3);
    int mtile = logical & 3;                    // 4 x 128 oc
    int rest = logical >> 2;                    // 0..391
    int n0 = (rest % 98) * 128;
    int b = rest / 98;

    const half_t* Agl = Wq16s + (size_t)(mtile * 128) * 32;           // +kk*16384
    const half_t* Bgl = xT16 + ((size_t)b * 8 * HW + n0) * 32;        // +kk*401408

    int lrow = l >> 2, lj = l & 3;
    auto stage = [&](int buf, int kk) {
        #pragma unroll
        for (int i = 0; i < 2; ++i) {
            int row = w * 32 + i * 16 + lrow;
            int gs = lj ^ ((row >> 1) & 3);
            const half_t* sa = Agl + (size_t)kk * 16384 + (size_t)row * 32 + gs * 8;
            const half_t* sb = Bgl + (size_t)kk * 401408 + (size_t)row * 32 + gs * 8;
            half_t* da = &As[buf][(w * 32 + i * 16) * 32];
            half_t* db = &Bs[buf][(w * 32 + i * 16) * 32];
            __builtin_amdgcn_global_load_lds(
                (const __attribute__((address_space(1))) void*)sa,
                (__attribute__((address_space(3))) void*)da, 16, 0, 0);
            __builtin_amdgcn_global_load_lds(
                (const __attribute__((address_space(1))) void*)sb,
                (__attribute__((address_space(3))) void*)db, 16, 0, 0);
        }
    };

    stage(0, 0);
    __syncthreads();

    f32x4 sc[4][4];
    #pragma unroll
    for (int a = 0; a < 4; ++a)
        #pragma unroll
        for (int nt = 0; nt < 4; ++nt) sc[a][nt] = (f32x4){0.f, 0.f, 0.f, 0.f};

    int qm = w >> 1, qn = w & 1;
    int rsw = (c >> 1) & 3;

    for (int kk = 0; kk < 8; ++kk) {
        int cur = kk & 1;
        if (kk + 1 < 8) stage(cur ^ 1, kk + 1);
        half8 af[4], bf[4];
        #pragma unroll
        for (int a = 0; a < 4; ++a) {
            int row = qm * 64 + a * 16 + c;
            af[a] = *(const half8*)&As[cur][row * 32 + ((g ^ rsw) << 3)];
        }
        #pragma unroll
        for (int nt = 0; nt < 4; ++nt) {
            int row = qn * 64 + nt * 16 + c;
            bf[nt] = *(const half8*)&Bs[cur][row * 32 + ((g ^ rsw) << 3)];
        }
        __builtin_amdgcn_s_setprio(1);
        #pragma unroll
        for (int a = 0; a < 4; ++a)
            #pragma unroll
            for (int nt = 0; nt < 4; ++nt)
                sc[a][nt] = __builtin_amdgcn_mfma_f32_16x16x32_f16(af[a], bf[nt], sc[a][nt], 0, 0, 0);
        __builtin_amdgcn_s_setprio(0);
        __syncthreads();
    }
    int h = mtile * 2 + qm;
    half_t* op = qtok + ((size_t)(b * HEADS + h) * HW + n0 + qn * 64 + c) * 64 + g * 4;
    #pragma unroll
    for (int a = 0; a < 4; ++a)
        #pragma unroll
        for (int nt = 0; nt < 4; ++nt) {
            uint2 u = make_uint2(pk2(sc[a][nt][0], sc[a][nt][1]),
                                 pk2(sc[a][nt][2], sc[a][nt][3]));
            *(uint2*)&op[(size_t)(nt * 16) * 64 + a * 16] = u;
        }
}

// ---------------- K2: KV conv GEMM, m97 template, split-K=8 (512 blocks = 2.0/CU, no tail)
__global__ __launch_bounds__(256) void k2_kv(const half_t* __restrict__ W16,
                                             const half_t* __restrict__ Pt,
                                             float* __restrict__ partial) {
    __shared__ half_t As[2][128 * 32];
    __shared__ half_t Bs[2][128 * 32];
    int t = threadIdx.x;
    int w = t >> 6, l = t & 63, g = l >> 4, c = l & 15;
    int bid = blockIdx.x;                       // grid 512 = 8 * 64
    int logical = (bid & 7) * 64 + (bid >> 3);
    int mtile = logical & 7;                    // 8 x 128 oc (B-panel sibs, same XCD)
    int rest = logical >> 3;                    // 0..63
    int ntile = rest & 1;                       // 2 x 128 pos
    int grp = rest >> 1;                        // 0..31 = ks*4 + b
    int ks = grp >> 2;
    int b = grp & 3;

    const half_t* Agl = W16 + ((size_t)(ks * 49) * 1024 + mtile * 128) * 32;
    const half_t* Bgl = Pt + (((size_t)b * 392 + ks * 49) * 256 + ntile * 128) * 32;

    int lrow = l >> 2, lj = l & 3;
    auto stage = [&](int buf, int kk) {
        #pragma unroll
        for (int i = 0; i < 2; ++i) {
            int row = w * 32 + i * 16 + lrow;
            int gs = lj ^ ((row >> 1) & 3);
            const half_t* sa = Agl + (size_t)kk * 32768 + (size_t)row * 32 + gs * 8;
            const half_t* sb = Bgl + (size_t)kk * 8192 + (size_t)row * 32 + gs * 8;
            half_t* da = &As[buf][(w * 32 + i * 16) * 32];
            half_t* db = &Bs[buf][(w * 32 + i * 16) * 32];
            __builtin_amdgcn_global_load_lds(
                (const __attribute__((address_space(1))) void*)sa,
                (__attribute__((address_space(3))) void*)da, 16, 0, 0);
            __builtin_amdgcn_global_load_lds(
                (const __attribute__((address_space(1))) void*)sb,
                (__attribute__((address_space(3))) void*)db, 16, 0, 0);
        }
    };

    stage(0, 0);
    __syncthreads();

    f32x4 sc[4][4];
    #pragma unroll
    for (int a = 0; a < 4; ++a)
        #pragma unroll
        for (int nt = 0; nt < 4; ++nt) sc[a][nt] = (f32x4){0.f, 0.f, 0.f, 0.f};

    int qm = w >> 1, qn = w & 1;
    int rsw = (c >> 1) & 3;

    for (int kk = 0; kk < K2STEPS; ++kk) {
        int cur = kk & 1;
        if (kk + 1 < K2STEPS) stage(cur ^ 1, kk + 1);
        half8 af[4], bf[4];
        #pragma unroll
        for (int a = 0; a < 4; ++a) {
            int row = qm * 64 + a * 16 + c;
            af[a] = *(const half8*)&As[cur][row * 32 + ((g ^ rsw) << 3)];
        }
        #pragma unroll
        for (int nt = 0; nt < 4; ++nt) {
            int row = qn * 64 + nt * 16 + c;
            bf[nt] = *(const half8*)&Bs[cur][row * 32 + ((g ^ rsw) << 3)];
        }
        __builtin_amdgcn_s_setprio(1);
        #pragma unroll
        for (int a = 0; a < 4; ++a)
            #pragma unroll
            for (int nt = 0; nt < 4; ++nt)
                sc[a][nt] = __builtin_amdgcn_mfma_f32_16x16x32_f16(af[a], bf[nt], sc[a][nt], 0, 0, 0);
        __builtin_amdgcn_s_setprio(0);
        __syncthreads();
    }
    float* op = partial + ((size_t)grp * 1024 + mtile * 128 + qm * 64 + g * 4) * 256
                + ntile * 128 + qn * 64 + c;
    #pragma unroll
    for (int a = 0; a < 4; ++a)
        #pragma unroll
        for (int nt = 0; nt < 4; ++nt)
            #pragma unroll
            for (int r = 0; r < 4; ++r)
                op[(size_t)(a * 16 + r) * 256 + nt * 16] = sc[a][nt][r];
}

// ---------------- K2r: reduce partials -> PRE-SWIZZLED LDS images for k3:
//   kimg[bh][32KB]: byte(kv,d) = kv*128 + (((d>>3)<<4) ^ ((kv&7)<<4)) + (d&7)*2
//   vimg[bh][32KB]: byte(d,kv') = d*512 + (((kv'>>3)<<4) ^ ((d&7)<<4)) + (kv'&7)*2
//   with V columns permuted kv = 32a+16b+4g+r -> kv' = 32a+8g+4b+r (zero-shuffle PV)
__global__ __launch_bounds__(256) void k2r(const float* __restrict__ partial,
                                           char* __restrict__ kimg,
                                           char* __restrict__ vimg) {
    int pos = threadIdx.x;
    int oc0 = blockIdx.x * 8;
    int b = blockIdx.y;
    float v[8];
    #pragma unroll
    for (int j = 0; j < 8; ++j) {
        const float* src = partial + ((size_t)b * 1024 + oc0 + j) * 256 + pos;
        float s = 0.f;
        #pragma unroll
        for (int ksb = 0; ksb < KSPLIT; ++ksb) s += src[(size_t)ksb * 1048576];
        v[j] = s;
    }
    int h = (oc0 >> 6) & 7, d0 = oc0 & 63;
    if (oc0 < 512) {
        uint4 u = make_uint4(pk2(v[0], v[1]), pk2(v[2], v[3]),
                             pk2(v[4], v[5]), pk2(v[6], v[7]));
        size_t off = ((size_t)(b * HEADS + h) << 15) + pos * 128
                     + (((unsigned)(d0 * 2)) ^ ((unsigned)((pos & 7) << 4)));
        *(uint4*)(kimg + off) = u;
    } else {
        int posP = (pos & ~31) | (((pos >> 2) & 3) << 3) | (((pos >> 4) & 1) << 2) | (pos & 3);
        size_t base = ((size_t)(b * HEADS + h) << 15);
        #pragma unroll
        for (int j = 0; j < 8; ++j) {
            int d = d0 + j;
            size_t off = base + d * 512
                         + ((((unsigned)(posP >> 3) << 4)) ^ ((unsigned)((d & 7) << 4)))
                         + (posP & 7) * 2;
            *(half_t*)(vimg + off) = (half_t)v[j];
        }
    }
}

// ---------------- K3: fused attention, swapped QK^T AND swapped PV, exp2-direct softmax.
// K/V staged via global_load_lds from pre-swizzled images (linear copy, zero staging VALU).
__global__ __launch_bounds__(512) void k3_attn(const half_t* __restrict__ qtok,
                                               const char* __restrict__ kimg,
                                               const char* __restrict__ vimg,
                                               half_t* __restrict__ otok16) {
    extern __shared__ char lds[];
    char* K_lds = lds;
    char* V_lds = lds + 32768;
    int t = threadIdx.x;
    int w = t >> 6, l = t & 63, g = l >> 4, c = l & 15;
    int q0 = blockIdx.x * 128;
    int bh = blockIdx.y;

    const half_t* qp = qtok + ((size_t)bh * HW + q0 + w * 16 + c) * 64 + g * 8;
    half8 bq0 = *(const half8*)(qp);
    half8 bq1 = *(const half8*)(qp + 32);

    // stage K/V images: 8 waves x 4 rounds x 1KB each, lane-linear
    {
        const char* ksrc = kimg + ((size_t)bh << 15);
        const char* vsrc = vimg + ((size_t)bh << 15);
        int l16 = l * 16;
        #pragma unroll
        for (int j = 0; j < 4; ++j) {
            int off = (j * 8 + w) * 1024;
            __builtin_amdgcn_global_load_lds(
                (const __attribute__((address_space(1))) void*)(ksrc + off + l16),
                (__attribute__((address_space(3))) void*)(K_lds + off), 16, 0, 0);
            __builtin_amdgcn_global_load_lds(
                (const __attribute__((address_space(1))) void*)(vsrc + off + l16),
                (__attribute__((address_space(3))) void*)(V_lds + off), 16, 0, 0);
        }
    }
    __syncthreads();

    f32x4 sc[16];
    __builtin_amdgcn_s_setprio(1);
    #pragma unroll
    for (int nt = 0; nt < 16; ++nt) {
        int row = nt * 16 + c;
        const char* kp = K_lds + row * 128;
        unsigned sw = (unsigned)((row & 7) << 4);
        half8 a0 = *(const half8*)(kp + (((unsigned)(g * 16)) ^ sw));
        half8 a1 = *(const half8*)(kp + (((unsigned)(g * 16 + 64)) ^ sw));
        f32x4 acc = (f32x4){0.f, 0.f, 0.f, 0.f};
        acc = __builtin_amdgcn_mfma_f32_16x16x32_f16(a0, bq0, acc, 0, 0, 0);
        acc = __builtin_amdgcn_mfma_f32_16x16x32_f16(a1, bq1, acc, 0, 0, 0);
        sc[nt] = acc;
    }
    __builtin_amdgcn_s_setprio(0);

    // softmax, exp2-direct (S already scaled by log2e), raw v_exp_f32, no max-subtraction
    float s = 0.f;
    #pragma unroll
    for (int nt = 0; nt < 16; ++nt)
        #pragma unroll
        for (int r = 0; r < 4; ++r) {
            float e = __builtin_amdgcn_exp2f(sc[nt][r]);
            sc[nt][r] = e;
            s += e;
        }
    s += __shfl_xor(s, 16);
    s += __shfl_xor(s, 32);
    float inv = 1.f / s;

    f32x4 o[4];
    #pragma unroll
    for (int nt = 0; nt < 4; ++nt) o[nt] = (f32x4){0.f, 0.f, 0.f, 0.f};
    __builtin_amdgcn_s_setprio(1);
    #pragma unroll
    for (int ks = 0; ks < 8; ++ks) {
        union { unsigned u[4]; half8 h; } ap;
        ap.u[0] = pk2(sc[2 * ks][0], sc[2 * ks][1]);
        ap.u[1] = pk2(sc[2 * ks][2], sc[2 * ks][3]);
        ap.u[2] = pk2(sc[2 * ks + 1][0], sc[2 * ks + 1][1]);
        ap.u[3] = pk2(sc[2 * ks + 1][2], sc[2 * ks + 1][3]);
        #pragma unroll
        for (int dt = 0; dt < 4; ++dt) {
            int d = dt * 16 + c;
            half8 av = *(const half8*)(V_lds + d * 512 +
                                       (((unsigned)(ks * 64 + g * 16)) ^ ((unsigned)((d & 7) << 4))));
            o[dt] = __builtin_amdgcn_mfma_f32_16x16x32_f16(av, ap.h, o[dt], 0, 0, 0);
        }
    }
    __builtin_amdgcn_s_setprio(0);
    int b = bh >> 3, h = bh & 7;
    #pragma unroll
    for (int dt = 0; dt < 4; ++dt) {
        uint2 u = make_uint2(pk2(o[dt][0] * inv, o[dt][1] * inv),
                             pk2(o[dt][2] * inv, o[dt][3] * inv));
        size_t off = (((size_t)b * 16 + h * 2 + (dt >> 1)) * HW + q0 + w * 16 + c) * 32
                     + (size_t)(((dt & 1) * 2 + (g >> 1)) * 8 + (g & 1) * 4);
        *(uint2*)&otok16[off] = u;
    }
}

// ---------------- K4: output projection + bias, m97 template: 128x128 tile, K=512
__global__ __launch_bounds__(256) void k4_outproj(const half_t* __restrict__ Wout16,
                                                  const half_t* __restrict__ otok16,
                                                  const float* __restrict__ bout,
                                                  float* __restrict__ outp) {
    __shared__ half_t As[2][128 * 32];
    __shared__ half_t Bs[2][128 * 32];
    int t = threadIdx.x;
    int w = t >> 6, l = t & 63, g = l >> 4, c = l & 15;
    int bid = blockIdx.x;                       // grid 784 = 8 * 98
    int logical = (bid & 7) * 98 + (bid >> 3);
    int mtile = logical & 1;                    // 2 x 128 oc
    int rest = logical >> 1;                    // 0..391
    int n0 = (rest % 98) * 128;
    int b = rest / 98;

    const half_t* Agl = Wout16 + (size_t)(mtile * 128) * 32;           // +kk*8192
    const half_t* Bgl = otok16 + ((size_t)b * 16 * HW + n0) * 32;      // +kk*401408

    int lrow = l >> 2, lj = l & 3;
    auto stage = [&](int buf, int kk) {
        #pragma unroll
        for (int i = 0; i < 2; ++i) {
            int row = w * 32 + i * 16 + lrow;
            int gs = lj ^ ((row >> 1) & 3);
            const half_t* sa = Agl + (size_t)kk * 8192 + (size_t)row * 32 + gs * 8;
            const half_t* sb = Bgl + (size_t)kk * 401408 + (size_t)row * 32 + gs * 8;
            half_t* da = &As[buf][(w * 32 + i * 16) * 32];
            half_t* db = &Bs[buf][(w * 32 + i * 16) * 32];
            __builtin_amdgcn_global_load_lds(
                (const __attribute__((address_space(1))) void*)sa,
                (__attribute__((address_space(3))) void*)da, 16, 0, 0);
            __builtin_amdgcn_global_load_lds(
                (const __attribute__((address_space(1))) void*)sb,
                (__attribute__((address_space(3))) void*)db, 16, 0, 0);
        }
    };

    stage(0, 0);
    __syncthreads();

    f32x4 sc[4][4];
    #pragma unroll
    for (int a = 0; a < 4; ++a)
        #pragma unroll
        for (int nt = 0; nt < 4; ++nt) sc[a][nt] = (f32x4){0.f, 0.f, 0.f, 0.f};

    int qm = w >> 1, qn = w & 1;
    int rsw = (c >> 1) & 3;

    for (int kk = 0; kk < 16; ++kk) {
        int cur = kk & 1;
        if (kk + 1 < 16) stage(cur ^ 1, kk + 1);
        half8 af[4], bf[4];
        #pragma unroll
        for (int a = 0; a < 4; ++a) {
            int row = qm * 64 + a * 16 + c;
            af[a] = *(const half8*)&As[cur][row * 32 + ((g ^ rsw) << 3)];
        }
        #pragma unroll
        for (int nt = 0; nt < 4; ++nt) {
            int row = qn * 64 + nt * 16 + c;
            bf[nt] = *(const half8*)&Bs[cur][row * 32 + ((g ^ rsw) << 3)];
        }
        __builtin_amdgcn_s_setprio(1);
        #pragma unroll
        for (int a = 0; a < 4; ++a)
            #pragma unroll
            for (int nt = 0; nt < 4; ++nt)
                sc[a][nt] = __builtin_amdgcn_mfma_f32_16x16x32_f16(af[a], bf[nt], sc[a][nt], 0, 0, 0);
        __builtin_amdgcn_s_setprio(0);
        __syncthreads();
    }
    #pragma unroll
    for (int a = 0; a < 4; ++a) {
        int ocb = mtile * 128 + qm * 64 + a * 16 + g * 4;
        float b0 = bout[ocb], b1 = bout[ocb + 1], b2 = bout[ocb + 2], b3 = bout[ocb + 3];
        float* op = outp + ((size_t)b * DIM + ocb) * HW + n0 + qn * 64 + c;
        #pragma unroll
        for (int nt = 0; nt < 4; ++nt) {
            op[(size_t)0 * HW + nt * 16] = sc[a][nt][0] + b0;
            op[(size_t)1 * HW + nt * 16] = sc[a][nt][1] + b1;
            op[(size_t)2 * HW + nt * 16] = sc[a][nt][2] + b2;
            op[(size_t)3 * HW + nt * 16] = sc[a][nt][3] + b3;
        }
    }
}

extern "C" void kernel_launch(void* const* d_in, const int* in_sizes, int n_in,
                              void* d_out, int out_size, void* d_ws, size_t ws_size,
                              hipStream_t stream) {
    (void)in_sizes; (void)n_in; (void)out_size; (void)ws_size;
    const float* x = (const float*)d_in[0];
    const float* Wq = (const float*)d_in[1];
    const float* Wkv = (const float*)d_in[2];
    const float* Wout = (const float*)d_in[3];
    const float* bout = (const float*)d_in[4];
    float* outp = (float*)d_out;

    // Workspace layout (f32 units; partial 8 slices = 8,388,608 floats):
    //   partial f32 [0, 8,388,608)                    (dead after k2r)
    //   kimg  bytes [14,680,064, 14,942,208)          (1MB: 32 bh x 32KB LDS image)
    //   vimg  bytes [14,942,208, 15,204,352)          (1MB, permuted+swizzled)
    //   Wq16s  f16  [15,204,352, 15,269,888)          (frag-ready, QSCALE2 folded)
    //   Wout16 f16  [15,269,888, 15,335,424)          (frag-ready)
    //   Wkv16  f16  [15,335,424, 21,757,952)          (frag-ready, dead after k2)
    //   Pt     f16  [21,757,952, 28,180,480)          (frag-ready, dead after k2)
    //   otok16 f16  [15,335,424, 28,180,480)          (frag-ready, overlays Wkv16+Pt)
    //   xT16   f16  [28,180,480, 34,603,008)          (frag-ready, dead after k1)
    //   qtok   f16  [34,603,008, 47,448,064)
    float* ws = (float*)d_ws;
    float*  partial = ws;
    char*   kimg    = (char*)(ws + 14680064);
    char*   vimg    = (char*)(ws + 14942208);
    half_t* Wq16s   = (half_t*)(ws + 15204352);
    half_t* Wout16  = (half_t*)(ws + 15269888);
    half_t* Wkv16   = (half_t*)(ws + 15335424);
    half_t* Pt      = (half_t*)(ws + 21757952);
    half_t* otok16  = (half_t*)(ws + 15335424);
    half_t* xT16    = (half_t*)(ws + 28180480);
    half_t* qtok    = (half_t*)(ws + 34603008);

    hipFuncSetAttribute((const void*)k3_attn,
                        hipFuncAttributeMaxDynamicSharedMemorySize, 65536);
    hipFuncSetAttribute((const void*)k_prep,
                        hipFuncAttributeMaxDynamicSharedMemorySize, 106880);

    k_cvtall<<<dim3(6400), 256, 0, stream>>>(Wkv, Wq, Wout, Wkv16, Wq16s, Wout16);
    k_prep<<<dim3(16, 8, 4), 256, 106880, stream>>>(x, Pt, xT16);
    k2_kv<<<dim3(512), 256, 0, stream>>>(Wkv16, Pt, partial);
    k2r<<<dim3(128, 4), 256, 0, stream>>>(partial, kimg, vimg);
    k1_qproj<<<dim3(1568), 256, 0, stream>>>(Wq16s, xT16, qtok);
    k3_attn<<<dim3(98, 32), 512, 65536, stream>>>(qtok, kimg, vimg, otok16);
    k4_outproj<<<dim3(784), 256, 0, stream>>>(Wout16, otok16, bout, outp);
}

// Round 19
// 206.625 us; speedup vs baseline: 1.0926x; 1.0926x over previous
//
#include <hip/hip_runtime.h>

#define HEADS 8
#define DHEAD 64
#define QSCALE 0.125f        // 64^-0.5
#define QSCALE2 0.1803368801111204f  // QSCALE * log2(e): exp2-direct softmax
#define DIM 256
#define IMG 112
#define HW 12544        // 112*112
#define NKV 256         // 16*16
#define INNER 512
#define KCONV 12544     // 256*49
#define KSPLIT 8
#define KCHUNK 1568     // 12544/8
#define K2STEPS 49      // KCHUNK/32

typedef _Float16 half_t;
typedef _Float16 half8 __attribute__((ext_vector_type(8)));
typedef float f32x4 __attribute__((ext_vector_type(4)));

__device__ inline unsigned pk2(float a, float b) {
    union { half_t h[2]; unsigned u; } x;
    x.h[0] = (half_t)a; x.h[1] = (half_t)b;
    return x.u;
}

// ---------------- Kcvt-all: all three weight conversions in one launch.
// grid 6400: [0,6272) Wkv, [6272,6336) Wq (QSCALE2 folded), [6336,6400) Wout
__global__ __launch_bounds__(256) void k_cvtall(const float* __restrict__ Wkv,
                                                const float* __restrict__ Wq,
                                                const float* __restrict__ Wout,
                                                half_t* __restrict__ Wkv16,
                                                half_t* __restrict__ Wq16s,
                                                half_t* __restrict__ Wout16) {
    int bid = blockIdx.x;
    const float* W;
    half_t* W16;
    float scale;
    int OC, K, gid;
    if (bid < 6272) {
        W = Wkv; W16 = Wkv16; scale = 1.0f; OC = 1024; K = KCONV;
        gid = bid * 256 + threadIdx.x;
    } else if (bid < 6336) {
        W = Wq; W16 = Wq16s; scale = QSCALE2; OC = 512; K = DIM;
        gid = (bid - 6272) * 256 + threadIdx.x;
    } else {
        W = Wout; W16 = Wout16; scale = 1.0f; OC = 256; K = INNER;
        gid = (bid - 6336) * 256 + threadIdx.x;
    }
    int perRow = K >> 3;
    int oc = gid / perRow;
    int k0 = (gid - oc * perRow) * 8;
    const float* src = W + (size_t)oc * K + k0;
    float4 a = *(const float4*)src;
    float4 b = *(const float4*)(src + 4);
    half8 h = { (half_t)(a.x * scale), (half_t)(a.y * scale),
                (half_t)(a.z * scale), (half_t)(a.w * scale),
                (half_t)(b.x * scale), (half_t)(b.y * scale),
                (half_t)(b.z * scale), (half_t)(b.w * scale) };
    *(half8*)&W16[(((size_t)(k0 >> 5) * OC + oc) * 4 + ((k0 >> 3) & 3)) * 8] = h;
}

// ---------------- K0+Kx merged: im2col gather + x transpose (both stream x)
// grid 9408: [0,6272) gather -> Pt'[b][kk 392][pos][g][8]; [6272,9408) -> x' [b][kk 8][n][g][8]
__global__ __launch_bounds__(256) void k0_prep(const float* __restrict__ x,
                                               half_t* __restrict__ Pt,
                                               half_t* __restrict__ xT16) {
    __shared__ float tile[64 * 68];
    int bid = blockIdx.x;
    int t = threadIdx.x;
    if (bid < 6272) {
        int gid = bid * 256 + t;
        int bp = gid / 1568;
        int k8 = gid - bp * 1568;
        int b = bp >> 8, pos = bp & 255;
        int oy = pos >> 4, ox = pos & 15;
        const float* xb = x + (size_t)b * DIM * HW + (size_t)(oy * 7) * IMG + ox * 7;
        int k0 = k8 * 8;
        half8 hv;
        #pragma unroll
        for (int j = 0; j < 8; ++j) {
            int k = k0 + j;
            int cch = k / 49;
            int tap = k - cch * 49;
            int kh = tap / 7;
            int kw = tap - kh * 7;
            hv[j] = (half_t)xb[(size_t)cch * HW + kh * IMG + kw];
        }
        *(half8*)&Pt[((((size_t)b * 392 + (k0 >> 5)) * 256 + pos) * 4 + ((k0 >> 3) & 3)) * 8] = hv;
    } else {
        int idx = bid - 6272;
        int n0 = (idx % 196) * 64;
        int c0 = ((idx / 196) & 3) * 64;
        int b = idx / 784;
        #pragma unroll
        for (int i = 0; i < 4; ++i) {
            int f4 = t + i * 256;
            int r = f4 >> 4, c4 = (f4 & 15) << 2;
            *(float4*)&tile[r * 68 + c4] =
                *(const float4*)&x[((size_t)(b * DIM + c0 + r)) * HW + n0 + c4];
        }
        __syncthreads();
        #pragma unroll
        for (int i = 0; i < 2; ++i) {
            int idx2 = t + i * 256;
            int rr = idx2 >> 3, cc8 = (idx2 & 7) << 3;
            half8 h;
            #pragma unroll
            for (int j = 0; j < 8; ++j) h[j] = (half_t)tile[(cc8 + j) * 68 + rr];
            int ch = c0 + cc8;
            *(half8*)&xT16[((((size_t)b * 8 + (ch >> 5)) * HW + n0 + rr) * 4 + ((ch >> 3) & 3)) * 8] = h;
        }
    }
}

// ---------------- K1: Q projection, m97 template: 128x128 tile, gload_lds dbuf, K=256
__global__ __launch_bounds__(256) void k1_qproj(const half_t* __restrict__ Wq16s,
                                                const half_t* __restrict__ xT16,
                                                half_t* __restrict__ qtok) {
    __shared__ half_t As[2][128 * 32];
    __shared__ half_t Bs[2][128 * 32];
    int t = threadIdx.x;
    int w = t >> 6, l = t & 63, g = l >> 4, c = l & 15;
    int bid = blockIdx.x;                       // grid 1568 = 8 * 196
    int logical = (bid & 7) * 196 + (bid >> 3);
    int mtile = logical & 3;                    // 4 x 128 oc
    int rest = logical >> 2;                    // 0..391
    int n0 = (rest % 98) * 128;
    int b = rest / 98;

    const half_t* Agl = Wq16s + (size_t)(mtile * 128) * 32;           // +kk*16384
    const half_t* Bgl = xT16 + ((size_t)b * 8 * HW + n0) * 32;        // +kk*401408

    int lrow = l >> 2, lj = l & 3;
    auto stage = [&](int buf, int kk) {
        #pragma unroll
        for (int i = 0; i < 2; ++i) {
            int row = w * 32 + i * 16 + lrow;
            int gs = lj ^ ((row >> 1) & 3);
            const half_t* sa = Agl + (size_t)kk * 16384 + (size_t)row * 32 + gs * 8;
            const half_t* sb = Bgl + (size_t)kk * 401408 + (size_t)row * 32 + gs * 8;
            half_t* da = &As[buf][(w * 32 + i * 16) * 32];
            half_t* db = &Bs[buf][(w * 32 + i * 16) * 32];
            __builtin_amdgcn_global_load_lds(
                (const __attribute__((address_space(1))) void*)sa,
                (__attribute__((address_space(3))) void*)da, 16, 0, 0);
            __builtin_amdgcn_global_load_lds(
                (const __attribute__((address_space(1))) void*)sb,
                (__attribute__((address_space(3))) void*)db, 16, 0, 0);
        }
    };

    stage(0, 0);
    __syncthreads();

    f32x4 sc[4][4];
    #pragma unroll
    for (int a = 0; a < 4; ++a)
        #pragma unroll
        for (int nt = 0; nt < 4; ++nt) sc[a][nt] = (f32x4){0.f, 0.f, 0.f, 0.f};

    int qm = w >> 1, qn = w & 1;
    int rsw = (c >> 1) & 3;

    for (int kk = 0; kk < 8; ++kk) {
        int cur = kk & 1;
        if (kk + 1 < 8) stage(cur ^ 1, kk + 1);
        half8 af[4], bf[4];
        #pragma unroll
        for (int a = 0; a < 4; ++a) {
            int row = qm * 64 + a * 16 + c;
            af[a] = *(const half8*)&As[cur][row * 32 + ((g ^ rsw) << 3)];
        }
        #pragma unroll
        for (int nt = 0; nt < 4; ++nt) {
            int row = qn * 64 + nt * 16 + c;
            bf[nt] = *(const half8*)&Bs[cur][row * 32 + ((g ^ rsw) << 3)];
        }
        __builtin_amdgcn_s_setprio(1);
        #pragma unroll
        for (int a = 0; a < 4; ++a)
            #pragma unroll
            for (int nt = 0; nt < 4; ++nt)
                sc[a][nt] = __builtin_amdgcn_mfma_f32_16x16x32_f16(af[a], bf[nt], sc[a][nt], 0, 0, 0);
        __builtin_amdgcn_s_setprio(0);
        __syncthreads();
    }
    int h = mtile * 2 + qm;
    half_t* op = qtok + ((size_t)(b * HEADS + h) * HW + n0 + qn * 64 + c) * 64 + g * 4;
    #pragma unroll
    for (int a = 0; a < 4; ++a)
        #pragma unroll
        for (int nt = 0; nt < 4; ++nt) {
            uint2 u = make_uint2(pk2(sc[a][nt][0], sc[a][nt][1]),
                                 pk2(sc[a][nt][2], sc[a][nt][3]));
            *(uint2*)&op[(size_t)(nt * 16) * 64 + a * 16] = u;
        }
}

// ---------------- K2: KV conv GEMM, m97 template, split-K=8 (512 blocks = 2.0/CU, no tail)
__global__ __launch_bounds__(256) void k2_kv(const half_t* __restrict__ W16,
                                             const half_t* __restrict__ Pt,
                                             float* __restrict__ partial) {
    __shared__ half_t As[2][128 * 32];
    __shared__ half_t Bs[2][128 * 32];
    int t = threadIdx.x;
    int w = t >> 6, l = t & 63, g = l >> 4, c = l & 15;
    int bid = blockIdx.x;                       // grid 512 = 8 * 64
    int logical = (bid & 7) * 64 + (bid >> 3);
    int mtile = logical & 7;                    // 8 x 128 oc (B-panel sibs, same XCD)
    int rest = logical >> 3;                    // 0..63
    int ntile = rest & 1;                       // 2 x 128 pos
    int grp = rest >> 1;                        // 0..31 = ks*4 + b
    int ks = grp >> 2;
    int b = grp & 3;

    const half_t* Agl = W16 + ((size_t)(ks * 49) * 1024 + mtile * 128) * 32;
    const half_t* Bgl = Pt + (((size_t)b * 392 + ks * 49) * 256 + ntile * 128) * 32;

    int lrow = l >> 2, lj = l & 3;
    auto stage = [&](int buf, int kk) {
        #pragma unroll
        for (int i = 0; i < 2; ++i) {
            int row = w * 32 + i * 16 + lrow;
            int gs = lj ^ ((row >> 1) & 3);
            const half_t* sa = Agl + (size_t)kk * 32768 + (size_t)row * 32 + gs * 8;
            const half_t* sb = Bgl + (size_t)kk * 8192 + (size_t)row * 32 + gs * 8;
            half_t* da = &As[buf][(w * 32 + i * 16) * 32];
            half_t* db = &Bs[buf][(w * 32 + i * 16) * 32];
            __builtin_amdgcn_global_load_lds(
                (const __attribute__((address_space(1))) void*)sa,
                (__attribute__((address_space(3))) void*)da, 16, 0, 0);
            __builtin_amdgcn_global_load_lds(
                (const __attribute__((address_space(1))) void*)sb,
                (__attribute__((address_space(3))) void*)db, 16, 0, 0);
        }
    };

    stage(0, 0);
    __syncthreads();

    f32x4 sc[4][4];
    #pragma unroll
    for (int a = 0; a < 4; ++a)
        #pragma unroll
        for (int nt = 0; nt < 4; ++nt) sc[a][nt] = (f32x4){0.f, 0.f, 0.f, 0.f};

    int qm = w >> 1, qn = w & 1;
    int rsw = (c >> 1) & 3;

    for (int kk = 0; kk < K2STEPS; ++kk) {
        int cur = kk & 1;
        if (kk + 1 < K2STEPS) stage(cur ^ 1, kk + 1);
        half8 af[4], bf[4];
        #pragma unroll
        for (int a = 0; a < 4; ++a) {
            int row = qm * 64 + a * 16 + c;
            af[a] = *(const half8*)&As[cur][row * 32 + ((g ^ rsw) << 3)];
        }
        #pragma unroll
        for (int nt = 0; nt < 4; ++nt) {
            int row = qn * 64 + nt * 16 + c;
            bf[nt] = *(const half8*)&Bs[cur][row * 32 + ((g ^ rsw) << 3)];
        }
        __builtin_amdgcn_s_setprio(1);
        #pragma unroll
        for (int a = 0; a < 4; ++a)
            #pragma unroll
            for (int nt = 0; nt < 4; ++nt)
                sc[a][nt] = __builtin_amdgcn_mfma_f32_16x16x32_f16(af[a], bf[nt], sc[a][nt], 0, 0, 0);
        __builtin_amdgcn_s_setprio(0);
        __syncthreads();
    }
    float* op = partial + ((size_t)grp * 1024 + mtile * 128 + qm * 64 + g * 4) * 256
                + ntile * 128 + qn * 64 + c;
    #pragma unroll
    for (int a = 0; a < 4; ++a)
        #pragma unroll
        for (int nt = 0; nt < 4; ++nt)
            #pragma unroll
            for (int r = 0; r < 4; ++r)
                op[(size_t)(a * 16 + r) * 256 + nt * 16] = sc[a][nt][r];
}

// ---------------- K2r: reduce partials -> PRE-SWIZZLED LDS images for k3:
//   kimg[bh][32KB]: byte(kv,d) = kv*128 + (((d>>3)<<4) ^ ((kv&7)<<4)) + (d&7)*2
//   vimg[bh][32KB]: byte(d,kv') = d*512 + (((kv'>>3)<<4) ^ ((d&7)<<4)) + (kv'&7)*2
//   with V columns permuted kv = 32a+16b+4g+r -> kv' = 32a+8g+4b+r (zero-shuffle PV)
__global__ __launch_bounds__(256) void k2r(const float* __restrict__ partial,
                                           char* __restrict__ kimg,
                                           char* __restrict__ vimg) {
    int pos = threadIdx.x;
    int oc0 = blockIdx.x * 8;
    int b = blockIdx.y;
    float v[8];
    #pragma unroll
    for (int j = 0; j < 8; ++j) {
        const float* src = partial + ((size_t)b * 1024 + oc0 + j) * 256 + pos;
        float s = 0.f;
        #pragma unroll
        for (int ksb = 0; ksb < KSPLIT; ++ksb) s += src[(size_t)ksb * 1048576];
        v[j] = s;
    }
    int h = (oc0 >> 6) & 7, d0 = oc0 & 63;
    if (oc0 < 512) {
        uint4 u = make_uint4(pk2(v[0], v[1]), pk2(v[2], v[3]),
                             pk2(v[4], v[5]), pk2(v[6], v[7]));
        size_t off = ((size_t)(b * HEADS + h) << 15) + pos * 128
                     + (((unsigned)(d0 * 2)) ^ ((unsigned)((pos & 7) << 4)));
        *(uint4*)(kimg + off) = u;
    } else {
        int posP = (pos & ~31) | (((pos >> 2) & 3) << 3) | (((pos >> 4) & 1) << 2) | (pos & 3);
        size_t base = ((size_t)(b * HEADS + h) << 15);
        #pragma unroll
        for (int j = 0; j < 8; ++j) {
            int d = d0 + j;
            size_t off = base + d * 512
                         + ((((unsigned)(posP >> 3) << 4)) ^ ((unsigned)((d & 7) << 4)))
                         + (posP & 7) * 2;
            *(half_t*)(vimg + off) = (half_t)v[j];
        }
    }
}

// ---------------- K3: fused attention, swapped QK^T AND swapped PV, exp2-direct softmax.
// K/V staged via global_load_lds from pre-swizzled images (linear copy, zero staging VALU).
__global__ __launch_bounds__(512) void k3_attn(const half_t* __restrict__ qtok,
                                               const char* __restrict__ kimg,
                                               const char* __restrict__ vimg,
                                               half_t* __restrict__ otok16) {
    extern __shared__ char lds[];
    char* K_lds = lds;
    char* V_lds = lds + 32768;
    int t = threadIdx.x;
    int w = t >> 6, l = t & 63, g = l >> 4, c = l & 15;
    int q0 = blockIdx.x * 128;
    int bh = blockIdx.y;

    const half_t* qp = qtok + ((size_t)bh * HW + q0 + w * 16 + c) * 64 + g * 8;
    half8 bq0 = *(const half8*)(qp);
    half8 bq1 = *(const half8*)(qp + 32);

    // stage K/V images: 8 waves x 4 rounds x 1KB each, lane-linear
    {
        const char* ksrc = kimg + ((size_t)bh << 15);
        const char* vsrc = vimg + ((size_t)bh << 15);
        int l16 = l * 16;
        #pragma unroll
        for (int j = 0; j < 4; ++j) {
            int off = (j * 8 + w) * 1024;
            __builtin_amdgcn_global_load_lds(
                (const __attribute__((address_space(1))) void*)(ksrc + off + l16),
                (__attribute__((address_space(3))) void*)(K_lds + off), 16, 0, 0);
            __builtin_amdgcn_global_load_lds(
                (const __attribute__((address_space(1))) void*)(vsrc + off + l16),
                (__attribute__((address_space(3))) void*)(V_lds + off), 16, 0, 0);
        }
    }
    __syncthreads();

    f32x4 sc[16];
    __builtin_amdgcn_s_setprio(1);
    #pragma unroll
    for (int nt = 0; nt < 16; ++nt) {
        int row = nt * 16 + c;
        const char* kp = K_lds + row * 128;
        unsigned sw = (unsigned)((row & 7) << 4);
        half8 a0 = *(const half8*)(kp + (((unsigned)(g * 16)) ^ sw));
        half8 a1 = *(const half8*)(kp + (((unsigned)(g * 16 + 64)) ^ sw));
        f32x4 acc = (f32x4){0.f, 0.f, 0.f, 0.f};
        acc = __builtin_amdgcn_mfma_f32_16x16x32_f16(a0, bq0, acc, 0, 0, 0);
        acc = __builtin_amdgcn_mfma_f32_16x16x32_f16(a1, bq1, acc, 0, 0, 0);
        sc[nt] = acc;
    }
    __builtin_amdgcn_s_setprio(0);

    // softmax, exp2-direct (S already scaled by log2e), raw v_exp_f32, no max-subtraction
    float s = 0.f;
    #pragma unroll
    for (int nt = 0; nt < 16; ++nt)
        #pragma unroll
        for (int r = 0; r < 4; ++r) {
            float e = __builtin_amdgcn_exp2f(sc[nt][r]);
            sc[nt][r] = e;
            s += e;
        }
    s += __shfl_xor(s, 16);
    s += __shfl_xor(s, 32);
    float inv = 1.f / s;

    f32x4 o[4];
    #pragma unroll
    for (int nt = 0; nt < 4; ++nt) o[nt] = (f32x4){0.f, 0.f, 0.f, 0.f};
    __builtin_amdgcn_s_setprio(1);
    #pragma unroll
    for (int ks = 0; ks < 8; ++ks) {
        union { unsigned u[4]; half8 h; } ap;
        ap.u[0] = pk2(sc[2 * ks][0], sc[2 * ks][1]);
        ap.u[1] = pk2(sc[2 * ks][2], sc[2 * ks][3]);
        ap.u[2] = pk2(sc[2 * ks + 1][0], sc[2 * ks + 1][1]);
        ap.u[3] = pk2(sc[2 * ks + 1][2], sc[2 * ks + 1][3]);
        #pragma unroll
        for (int dt = 0; dt < 4; ++dt) {
            int d = dt * 16 + c;
            half8 av = *(const half8*)(V_lds + d * 512 +
                                       (((unsigned)(ks * 64 + g * 16)) ^ ((unsigned)((d & 7) << 4))));
            o[dt] = __builtin_amdgcn_mfma_f32_16x16x32_f16(av, ap.h, o[dt], 0, 0, 0);
        }
    }
    __builtin_amdgcn_s_setprio(0);
    int b = bh >> 3, h = bh & 7;
    #pragma unroll
    for (int dt = 0; dt < 4; ++dt) {
        uint2 u = make_uint2(pk2(o[dt][0] * inv, o[dt][1] * inv),
                             pk2(o[dt][2] * inv, o[dt][3] * inv));
        size_t off = (((size_t)b * 16 + h * 2 + (dt >> 1)) * HW + q0 + w * 16 + c) * 32
                     + (size_t)(((dt & 1) * 2 + (g >> 1)) * 8 + (g & 1) * 4);
        *(uint2*)&otok16[off] = u;
    }
}

// ---------------- K4: output projection + bias, m97 template: 128x128 tile, K=512
__global__ __launch_bounds__(256) void k4_outproj(const half_t* __restrict__ Wout16,
                                                  const half_t* __restrict__ otok16,
                                                  const float* __restrict__ bout,
                                                  float* __restrict__ outp) {
    __shared__ half_t As[2][128 * 32];
    __shared__ half_t Bs[2][128 * 32];
    int t = threadIdx.x;
    int w = t >> 6, l = t & 63, g = l >> 4, c = l & 15;
    int bid = blockIdx.x;                       // grid 784 = 8 * 98
    int logical = (bid & 7) * 98 + (bid >> 3);
    int mtile = logical & 1;                    // 2 x 128 oc
    int rest = logical >> 1;                    // 0..391
    int n0 = (rest % 98) * 128;
    int b = rest / 98;

    const half_t* Agl = Wout16 + (size_t)(mtile * 128) * 32;           // +kk*8192
    const half_t* Bgl = otok16 + ((size_t)b * 16 * HW + n0) * 32;      // +kk*401408

    int lrow = l >> 2, lj = l & 3;
    auto stage = [&](int buf, int kk) {
        #pragma unroll
        for (int i = 0; i < 2; ++i) {
            int row = w * 32 + i * 16 + lrow;
            int gs = lj ^ ((row >> 1) & 3);
            const half_t* sa = Agl + (size_t)kk * 8192 + (size_t)row * 32 + gs * 8;
            const half_t* sb = Bgl + (size_t)kk * 401408 + (size_t)row * 32 + gs * 8;
            half_t* da = &As[buf][(w * 32 + i * 16) * 32];
            half_t* db = &Bs[buf][(w * 32 + i * 16) * 32];
            __builtin_amdgcn_global_load_lds(
                (const __attribute__((address_space(1))) void*)sa,
                (__attribute__((address_space(3))) void*)da, 16, 0, 0);
            __builtin_amdgcn_global_load_lds(
                (const __attribute__((address_space(1))) void*)sb,
                (__attribute__((address_space(3))) void*)db, 16, 0, 0);
        }
    };

    stage(0, 0);
    __syncthreads();

    f32x4 sc[4][4];
    #pragma unroll
    for (int a = 0; a < 4; ++a)
        #pragma unroll
        for (int nt = 0; nt < 4; ++nt) sc[a][nt] = (f32x4){0.f, 0.f, 0.f, 0.f};

    int qm = w >> 1, qn = w & 1;
    int rsw = (c >> 1) & 3;

    for (int kk = 0; kk < 16; ++kk) {
        int cur = kk & 1;
        if (kk + 1 < 16) stage(cur ^ 1, kk + 1);
        half8 af[4], bf[4];
        #pragma unroll
        for (int a = 0; a < 4; ++a) {
            int row = qm * 64 + a * 16 + c;
            af[a] = *(const half8*)&As[cur][row * 32 + ((g ^ rsw) << 3)];
        }
        #pragma unroll
        for (int nt = 0; nt < 4; ++nt) {
            int row = qn * 64 + nt * 16 + c;
            bf[nt] = *(const half8*)&Bs[cur][row * 32 + ((g ^ rsw) << 3)];
        }
        __builtin_amdgcn_s_setprio(1);
        #pragma unroll
        for (int a = 0; a < 4; ++a)
            #pragma unroll
            for (int nt = 0; nt < 4; ++nt)
                sc[a][nt] = __builtin_amdgcn_mfma_f32_16x16x32_f16(af[a], bf[nt], sc[a][nt], 0, 0, 0);
        __builtin_amdgcn_s_setprio(0);
        __syncthreads();
    }
    #pragma unroll
    for (int a = 0; a < 4; ++a) {
        int ocb = mtile * 128 + qm * 64 + a * 16 + g * 4;
        float b0 = bout[ocb], b1 = bout[ocb + 1], b2 = bout[ocb + 2], b3 = bout[ocb + 3];
        float* op = outp + ((size_t)b * DIM + ocb) * HW + n0 + qn * 64 + c;
        #pragma unroll
        for (int nt = 0; nt < 4; ++nt) {
            op[(size_t)0 * HW + nt * 16] = sc[a][nt][0] + b0;
            op[(size_t)1 * HW + nt * 16] = sc[a][nt][1] + b1;
            op[(size_t)2 * HW + nt * 16] = sc[a][nt][2] + b2;
            op[(size_t)3 * HW + nt * 16] = sc[a][nt][3] + b3;
        }
    }
}

extern "C" void kernel_launch(void* const* d_in, const int* in_sizes, int n_in,
                              void* d_out, int out_size, void* d_ws, size_t ws_size,
                              hipStream_t stream) {
    (void)in_sizes; (void)n_in; (void)out_size; (void)ws_size;
    const float* x = (const float*)d_in[0];
    const float* Wq = (const float*)d_in[1];
    const float* Wkv = (const float*)d_in[2];
    const float* Wout = (const float*)d_in[3];
    const float* bout = (const float*)d_in[4];
    float* outp = (float*)d_out;

    // Workspace layout (f32 units; partial 8 slices = 8,388,608 floats):
    //   partial f32 [0, 8,388,608)                    (dead after k2r)
    //   kimg  bytes [14,680,064, 14,942,208)          (1MB: 32 bh x 32KB LDS image)
    //   vimg  bytes [14,942,208, 15,204,352)          (1MB, permuted+swizzled)
    //   Wq16s  f16  [15,204,352, 15,269,888)          (frag-ready, QSCALE2 folded)
    //   Wout16 f16  [15,269,888, 15,335,424)          (frag-ready)
    //   Wkv16  f16  [15,335,424, 21,757,952)          (frag-ready, dead after k2)
    //   Pt     f16  [21,757,952, 28,180,480)          (frag-ready, dead after k2)
    //   otok16 f16  [15,335,424, 28,180,480)          (frag-ready, overlays Wkv16+Pt)
    //   xT16   f16  [28,180,480, 34,603,008)          (frag-ready, dead after k1)
    //   qtok   f16  [34,603,008, 47,448,064)
    float* ws = (float*)d_ws;
    float*  partial = ws;
    char*   kimg    = (char*)(ws + 14680064);
    char*   vimg    = (char*)(ws + 14942208);
    half_t* Wq16s   = (half_t*)(ws + 15204352);
    half_t* Wout16  = (half_t*)(ws + 15269888);
    half_t* Wkv16   = (half_t*)(ws + 15335424);
    half_t* Pt      = (half_t*)(ws + 21757952);
    half_t* otok16  = (half_t*)(ws + 15335424);
    half_t* xT16    = (half_t*)(ws + 28180480);
    half_t* qtok    = (half_t*)(ws + 34603008);

    hipFuncSetAttribute((const void*)k3_attn,
                        hipFuncAttributeMaxDynamicSharedMemorySize, 65536);

    k_cvtall<<<dim3(6400), 256, 0, stream>>>(Wkv, Wq, Wout, Wkv16, Wq16s, Wout16);
    k0_prep<<<dim3(9408), 256, 0, stream>>>(x, Pt, xT16);
    k2_kv<<<dim3(512), 256, 0, stream>>>(Wkv16, Pt, partial);
    k2r<<<dim3(128, 4), 256, 0, stream>>>(partial, kimg, vimg);
    k1_qproj<<<dim3(1568), 256, 0, stream>>>(Wq16s, xT16, qtok);
    k3_attn<<<dim3(98, 32), 512, 65536, stream>>>(qtok, kimg, vimg, otok16);
    k4_outproj<<<dim3(784), 256, 0, stream>>>(Wout16, otok16, bout, outp);
}

// Round 20
// 191.024 us; speedup vs baseline: 1.1818x; 1.0817x over previous
//
#include <hip/hip_runtime.h>

#define HEADS 8
#define DHEAD 64
#define QSCALE 0.125f        // 64^-0.5
#define QSCALE2 0.1803368801111204f  // QSCALE * log2(e): exp2-direct softmax
#define DIM 256
#define IMG 112
#define HW 12544        // 112*112
#define NKV 256         // 16*16
#define INNER 512
#define KCONV 12544     // 256*49
#define KSPLIT 8
#define KCHUNK 1568     // 12544/8
#define K2STEPS 49      // KCHUNK/32

typedef _Float16 half_t;
typedef _Float16 half8 __attribute__((ext_vector_type(8)));
typedef float f32x4 __attribute__((ext_vector_type(4)));

__device__ inline unsigned pk2(float a, float b) {
    union { half_t h[2]; unsigned u; } x;
    x.h[0] = (half_t)a; x.h[1] = (half_t)b;
    return x.u;
}

// ---------------- K_front: weight cvt (3x) + im2col gather + x transpose, one launch.
// grid 15808: [0,6272) Wkv cvt, [6272,6336) Wq cvt, [6336,6400) Wout cvt,
//             [6400,12672) gather -> Pt', [12672,15808) transpose -> x'
__global__ __launch_bounds__(256) void k_front(const float* __restrict__ x,
                                               const float* __restrict__ Wkv,
                                               const float* __restrict__ Wq,
                                               const float* __restrict__ Wout,
                                               half_t* __restrict__ Wkv16,
                                               half_t* __restrict__ Wq16s,
                                               half_t* __restrict__ Wout16,
                                               half_t* __restrict__ Pt,
                                               half_t* __restrict__ xT16) {
    __shared__ float tile[64 * 68];
    int bid = blockIdx.x;
    int t = threadIdx.x;
    if (bid < 6400) {
        // weight conversion
        const float* W;
        half_t* W16;
        float scale;
        int OC, K, gid;
        if (bid < 6272) {
            W = Wkv; W16 = Wkv16; scale = 1.0f; OC = 1024; K = KCONV;
            gid = bid * 256 + t;
        } else if (bid < 6336) {
            W = Wq; W16 = Wq16s; scale = QSCALE2; OC = 512; K = DIM;
            gid = (bid - 6272) * 256 + t;
        } else {
            W = Wout; W16 = Wout16; scale = 1.0f; OC = 256; K = INNER;
            gid = (bid - 6336) * 256 + t;
        }
        int perRow = K >> 3;
        int oc = gid / perRow;
        int k0 = (gid - oc * perRow) * 8;
        const float* src = W + (size_t)oc * K + k0;
        float4 a = *(const float4*)src;
        float4 b = *(const float4*)(src + 4);
        half8 h = { (half_t)(a.x * scale), (half_t)(a.y * scale),
                    (half_t)(a.z * scale), (half_t)(a.w * scale),
                    (half_t)(b.x * scale), (half_t)(b.y * scale),
                    (half_t)(b.z * scale), (half_t)(b.w * scale) };
        *(half8*)&W16[(((size_t)(k0 >> 5) * OC + oc) * 4 + ((k0 >> 3) & 3)) * 8] = h;
    } else if (bid < 12672) {
        // im2col gather -> Pt'[b][kk 392][pos][g][8]
        int gid = (bid - 6400) * 256 + t;
        int bp = gid / 1568;
        int k8 = gid - bp * 1568;
        int b = bp >> 8, pos = bp & 255;
        int oy = pos >> 4, ox = pos & 15;
        const float* xb = x + (size_t)b * DIM * HW + (size_t)(oy * 7) * IMG + ox * 7;
        int k0 = k8 * 8;
        half8 hv;
        #pragma unroll
        for (int j = 0; j < 8; ++j) {
            int k = k0 + j;
            int cch = k / 49;
            int tap = k - cch * 49;
            int kh = tap / 7;
            int kw = tap - kh * 7;
            hv[j] = (half_t)xb[(size_t)cch * HW + kh * IMG + kw];
        }
        *(half8*)&Pt[((((size_t)b * 392 + (k0 >> 5)) * 256 + pos) * 4 + ((k0 >> 3) & 3)) * 8] = hv;
    } else {
        // x transpose -> x'[b][kk 8][n][g][8]
        int idx = bid - 12672;
        int n0 = (idx % 196) * 64;
        int c0 = ((idx / 196) & 3) * 64;
        int b = idx / 784;
        #pragma unroll
        for (int i = 0; i < 4; ++i) {
            int f4 = t + i * 256;
            int r = f4 >> 4, c4 = (f4 & 15) << 2;
            *(float4*)&tile[r * 68 + c4] =
                *(const float4*)&x[((size_t)(b * DIM + c0 + r)) * HW + n0 + c4];
        }
        __syncthreads();
        #pragma unroll
        for (int i = 0; i < 2; ++i) {
            int idx2 = t + i * 256;
            int rr = idx2 >> 3, cc8 = (idx2 & 7) << 3;
            half8 h;
            #pragma unroll
            for (int j = 0; j < 8; ++j) h[j] = (half_t)tile[(cc8 + j) * 68 + rr];
            int ch = c0 + cc8;
            *(half8*)&xT16[((((size_t)b * 8 + (ch >> 5)) * HW + n0 + rr) * 4 + ((ch >> 3) & 3)) * 8] = h;
        }
    }
}

// ---------------- K_mid: k2 (KV conv GEMM, split-K=8) + k1 (Q proj), one launch.
// grid 2080: [0,512) k2; [512,2080) k1. Both m97 template, 128x128 tile, gload_lds dbuf.
__global__ __launch_bounds__(256) void k_mid(const half_t* __restrict__ Wkv16,
                                             const half_t* __restrict__ Pt,
                                             float* __restrict__ partial,
                                             const half_t* __restrict__ Wq16s,
                                             const half_t* __restrict__ xT16,
                                             half_t* __restrict__ qtok) {
    __shared__ half_t As[2][128 * 32];
    __shared__ half_t Bs[2][128 * 32];
    int t = threadIdx.x;
    int w = t >> 6, l = t & 63, g = l >> 4, c = l & 15;
    int lrow = l >> 2, lj = l & 3;
    int qm = w >> 1, qn = w & 1;
    int rsw = (c >> 1) & 3;
    int bid = blockIdx.x;

    if (bid < 512) {
        // ---- k2 body ----
        int logical = (bid & 7) * 64 + (bid >> 3);
        int mtile = logical & 7;
        int rest = logical >> 3;
        int ntile = rest & 1;
        int grp = rest >> 1;                    // = ks*4 + b
        int ks = grp >> 2;
        int b = grp & 3;

        const half_t* Agl = Wkv16 + ((size_t)(ks * 49) * 1024 + mtile * 128) * 32;
        const half_t* Bgl = Pt + (((size_t)b * 392 + ks * 49) * 256 + ntile * 128) * 32;

        auto stage = [&](int buf, int kk) {
            #pragma unroll
            for (int i = 0; i < 2; ++i) {
                int row = w * 32 + i * 16 + lrow;
                int gs = lj ^ ((row >> 1) & 3);
                const half_t* sa = Agl + (size_t)kk * 32768 + (size_t)row * 32 + gs * 8;
                const half_t* sb = Bgl + (size_t)kk * 8192 + (size_t)row * 32 + gs * 8;
                half_t* da = &As[buf][(w * 32 + i * 16) * 32];
                half_t* db = &Bs[buf][(w * 32 + i * 16) * 32];
                __builtin_amdgcn_global_load_lds(
                    (const __attribute__((address_space(1))) void*)sa,
                    (__attribute__((address_space(3))) void*)da, 16, 0, 0);
                __builtin_amdgcn_global_load_lds(
                    (const __attribute__((address_space(1))) void*)sb,
                    (__attribute__((address_space(3))) void*)db, 16, 0, 0);
            }
        };

        stage(0, 0);
        __syncthreads();

        f32x4 sc[4][4];
        #pragma unroll
        for (int a = 0; a < 4; ++a)
            #pragma unroll
            for (int nt = 0; nt < 4; ++nt) sc[a][nt] = (f32x4){0.f, 0.f, 0.f, 0.f};

        for (int kk = 0; kk < K2STEPS; ++kk) {
            int cur = kk & 1;
            if (kk + 1 < K2STEPS) stage(cur ^ 1, kk + 1);
            half8 af[4], bf[4];
            #pragma unroll
            for (int a = 0; a < 4; ++a) {
                int row = qm * 64 + a * 16 + c;
                af[a] = *(const half8*)&As[cur][row * 32 + ((g ^ rsw) << 3)];
            }
            #pragma unroll
            for (int nt = 0; nt < 4; ++nt) {
                int row = qn * 64 + nt * 16 + c;
                bf[nt] = *(const half8*)&Bs[cur][row * 32 + ((g ^ rsw) << 3)];
            }
            __builtin_amdgcn_s_setprio(1);
            #pragma unroll
            for (int a = 0; a < 4; ++a)
                #pragma unroll
                for (int nt = 0; nt < 4; ++nt)
                    sc[a][nt] = __builtin_amdgcn_mfma_f32_16x16x32_f16(af[a], bf[nt], sc[a][nt], 0, 0, 0);
            __builtin_amdgcn_s_setprio(0);
            __syncthreads();
        }
        float* op = partial + ((size_t)grp * 1024 + mtile * 128 + qm * 64 + g * 4) * 256
                    + ntile * 128 + qn * 64 + c;
        #pragma unroll
        for (int a = 0; a < 4; ++a)
            #pragma unroll
            for (int nt = 0; nt < 4; ++nt)
                #pragma unroll
                for (int r = 0; r < 4; ++r)
                    op[(size_t)(a * 16 + r) * 256 + nt * 16] = sc[a][nt][r];
    } else {
        // ---- k1 body ----
        int bl = bid - 512;                     // [0,1568)
        int logical = (bl & 7) * 196 + (bl >> 3);
        int mtile = logical & 3;
        int rest = logical >> 2;
        int n0 = (rest % 98) * 128;
        int b = rest / 98;

        const half_t* Agl = Wq16s + (size_t)(mtile * 128) * 32;
        const half_t* Bgl = xT16 + ((size_t)b * 8 * HW + n0) * 32;

        auto stage = [&](int buf, int kk) {
            #pragma unroll
            for (int i = 0; i < 2; ++i) {
                int row = w * 32 + i * 16 + lrow;
                int gs = lj ^ ((row >> 1) & 3);
                const half_t* sa = Agl + (size_t)kk * 16384 + (size_t)row * 32 + gs * 8;
                const half_t* sb = Bgl + (size_t)kk * 401408 + (size_t)row * 32 + gs * 8;
                half_t* da = &As[buf][(w * 32 + i * 16) * 32];
                half_t* db = &Bs[buf][(w * 32 + i * 16) * 32];
                __builtin_amdgcn_global_load_lds(
                    (const __attribute__((address_space(1))) void*)sa,
                    (__attribute__((address_space(3))) void*)da, 16, 0, 0);
                __builtin_amdgcn_global_load_lds(
                    (const __attribute__((address_space(1))) void*)sb,
                    (__attribute__((address_space(3))) void*)db, 16, 0, 0);
            }
        };

        stage(0, 0);
        __syncthreads();

        f32x4 sc[4][4];
        #pragma unroll
        for (int a = 0; a < 4; ++a)
            #pragma unroll
            for (int nt = 0; nt < 4; ++nt) sc[a][nt] = (f32x4){0.f, 0.f, 0.f, 0.f};

        for (int kk = 0; kk < 8; ++kk) {
            int cur = kk & 1;
            if (kk + 1 < 8) stage(cur ^ 1, kk + 1);
            half8 af[4], bf[4];
            #pragma unroll
            for (int a = 0; a < 4; ++a) {
                int row = qm * 64 + a * 16 + c;
                af[a] = *(const half8*)&As[cur][row * 32 + ((g ^ rsw) << 3)];
            }
            #pragma unroll
            for (int nt = 0; nt < 4; ++nt) {
                int row = qn * 64 + nt * 16 + c;
                bf[nt] = *(const half8*)&Bs[cur][row * 32 + ((g ^ rsw) << 3)];
            }
            __builtin_amdgcn_s_setprio(1);
            #pragma unroll
            for (int a = 0; a < 4; ++a)
                #pragma unroll
                for (int nt = 0; nt < 4; ++nt)
                    sc[a][nt] = __builtin_amdgcn_mfma_f32_16x16x32_f16(af[a], bf[nt], sc[a][nt], 0, 0, 0);
            __builtin_amdgcn_s_setprio(0);
            __syncthreads();
        }
        int h = mtile * 2 + qm;
        half_t* op = qtok + ((size_t)(b * HEADS + h) * HW + n0 + qn * 64 + c) * 64 + g * 4;
        #pragma unroll
        for (int a = 0; a < 4; ++a)
            #pragma unroll
            for (int nt = 0; nt < 4; ++nt) {
                uint2 u = make_uint2(pk2(sc[a][nt][0], sc[a][nt][1]),
                                     pk2(sc[a][nt][2], sc[a][nt][3]));
                *(uint2*)&op[(size_t)(nt * 16) * 64 + a * 16] = u;
            }
    }
}

// ---------------- K2r: reduce partials -> PRE-SWIZZLED LDS images for k3:
//   kimg[bh][32KB]: byte(kv,d) = kv*128 + (((d>>3)<<4) ^ ((kv&7)<<4)) + (d&7)*2
//   vimg[bh][32KB]: byte(d,kv') = d*512 + (((kv'>>3)<<4) ^ ((d&7)<<4)) + (kv'&7)*2
//   with V columns permuted kv = 32a+16b+4g+r -> kv' = 32a+8g+4b+r (zero-shuffle PV)
__global__ __launch_bounds__(256) void k2r(const float* __restrict__ partial,
                                           char* __restrict__ kimg,
                                           char* __restrict__ vimg) {
    int pos = threadIdx.x;
    int oc0 = blockIdx.x * 8;
    int b = blockIdx.y;
    float v[8];
    #pragma unroll
    for (int j = 0; j < 8; ++j) {
        const float* src = partial + ((size_t)b * 1024 + oc0 + j) * 256 + pos;
        float s = 0.f;
        #pragma unroll
        for (int ksb = 0; ksb < KSPLIT; ++ksb) s += src[(size_t)ksb * 1048576];
        v[j] = s;
    }
    int h = (oc0 >> 6) & 7, d0 = oc0 & 63;
    if (oc0 < 512) {
        uint4 u = make_uint4(pk2(v[0], v[1]), pk2(v[2], v[3]),
                             pk2(v[4], v[5]), pk2(v[6], v[7]));
        size_t off = ((size_t)(b * HEADS + h) << 15) + pos * 128
                     + (((unsigned)(d0 * 2)) ^ ((unsigned)((pos & 7) << 4)));
        *(uint4*)(kimg + off) = u;
    } else {
        int posP = (pos & ~31) | (((pos >> 2) & 3) << 3) | (((pos >> 4) & 1) << 2) | (pos & 3);
        size_t base = ((size_t)(b * HEADS + h) << 15);
        #pragma unroll
        for (int j = 0; j < 8; ++j) {
            int d = d0 + j;
            size_t off = base + d * 512
                         + ((((unsigned)(posP >> 3) << 4)) ^ ((unsigned)((d & 7) << 4)))
                         + (posP & 7) * 2;
            *(half_t*)(vimg + off) = (half_t)v[j];
        }
    }
}

// ---------------- K3: fused attention, swapped QK^T AND swapped PV, exp2-direct softmax.
// K/V staged via global_load_lds from pre-swizzled images (linear copy, zero staging VALU).
__global__ __launch_bounds__(512) void k3_attn(const half_t* __restrict__ qtok,
                                               const char* __restrict__ kimg,
                                               const char* __restrict__ vimg,
                                               half_t* __restrict__ otok16) {
    extern __shared__ char lds[];
    char* K_lds = lds;
    char* V_lds = lds + 32768;
    int t = threadIdx.x;
    int w = t >> 6, l = t & 63, g = l >> 4, c = l & 15;
    int q0 = blockIdx.x * 128;
    int bh = blockIdx.y;

    const half_t* qp = qtok + ((size_t)bh * HW + q0 + w * 16 + c) * 64 + g * 8;
    half8 bq0 = *(const half8*)(qp);
    half8 bq1 = *(const half8*)(qp + 32);

    // stage K/V images: 8 waves x 4 rounds x 1KB each, lane-linear
    {
        const char* ksrc = kimg + ((size_t)bh << 15);
        const char* vsrc = vimg + ((size_t)bh << 15);
        int l16 = l * 16;
        #pragma unroll
        for (int j = 0; j < 4; ++j) {
            int off = (j * 8 + w) * 1024;
            __builtin_amdgcn_global_load_lds(
                (const __attribute__((address_space(1))) void*)(ksrc + off + l16),
                (__attribute__((address_space(3))) void*)(K_lds + off), 16, 0, 0);
            __builtin_amdgcn_global_load_lds(
                (const __attribute__((address_space(1))) void*)(vsrc + off + l16),
                (__attribute__((address_space(3))) void*)(V_lds + off), 16, 0, 0);
        }
    }
    __syncthreads();

    f32x4 sc[16];
    __builtin_amdgcn_s_setprio(1);
    #pragma unroll
    for (int nt = 0; nt < 16; ++nt) {
        int row = nt * 16 + c;
        const char* kp = K_lds + row * 128;
        unsigned sw = (unsigned)((row & 7) << 4);
        half8 a0 = *(const half8*)(kp + (((unsigned)(g * 16)) ^ sw));
        half8 a1 = *(const half8*)(kp + (((unsigned)(g * 16 + 64)) ^ sw));
        f32x4 acc = (f32x4){0.f, 0.f, 0.f, 0.f};
        acc = __builtin_amdgcn_mfma_f32_16x16x32_f16(a0, bq0, acc, 0, 0, 0);
        acc = __builtin_amdgcn_mfma_f32_16x16x32_f16(a1, bq1, acc, 0, 0, 0);
        sc[nt] = acc;
    }
    __builtin_amdgcn_s_setprio(0);

    // softmax, exp2-direct (S already scaled by log2e), raw v_exp_f32, no max-subtraction
    float s = 0.f;
    #pragma unroll
    for (int nt = 0; nt < 16; ++nt)
        #pragma unroll
        for (int r = 0; r < 4; ++r) {
            float e = __builtin_amdgcn_exp2f(sc[nt][r]);
            sc[nt][r] = e;
            s += e;
        }
    s += __shfl_xor(s, 16);
    s += __shfl_xor(s, 32);
    float inv = 1.f / s;

    f32x4 o[4];
    #pragma unroll
    for (int nt = 0; nt < 4; ++nt) o[nt] = (f32x4){0.f, 0.f, 0.f, 0.f};
    __builtin_amdgcn_s_setprio(1);
    #pragma unroll
    for (int ks = 0; ks < 8; ++ks) {
        union { unsigned u[4]; half8 h; } ap;
        ap.u[0] = pk2(sc[2 * ks][0], sc[2 * ks][1]);
        ap.u[1] = pk2(sc[2 * ks][2], sc[2 * ks][3]);
        ap.u[2] = pk2(sc[2 * ks + 1][0], sc[2 * ks + 1][1]);
        ap.u[3] = pk2(sc[2 * ks + 1][2], sc[2 * ks + 1][3]);
        #pragma unroll
        for (int dt = 0; dt < 4; ++dt) {
            int d = dt * 16 + c;
            half8 av = *(const half8*)(V_lds + d * 512 +
                                       (((unsigned)(ks * 64 + g * 16)) ^ ((unsigned)((d & 7) << 4))));
            o[dt] = __builtin_amdgcn_mfma_f32_16x16x32_f16(av, ap.h, o[dt], 0, 0, 0);
        }
    }
    __builtin_amdgcn_s_setprio(0);
    int b = bh >> 3, h = bh & 7;
    #pragma unroll
    for (int dt = 0; dt < 4; ++dt) {
        uint2 u = make_uint2(pk2(o[dt][0] * inv, o[dt][1] * inv),
                             pk2(o[dt][2] * inv, o[dt][3] * inv));
        size_t off = (((size_t)b * 16 + h * 2 + (dt >> 1)) * HW + q0 + w * 16 + c) * 32
                     + (size_t)(((dt & 1) * 2 + (g >> 1)) * 8 + (g & 1) * 4);
        *(uint2*)&otok16[off] = u;
    }
}

// ---------------- K4: output projection + bias, m97 template: 128x128 tile, K=512
__global__ __launch_bounds__(256) void k4_outproj(const half_t* __restrict__ Wout16,
                                                  const half_t* __restrict__ otok16,
                                                  const float* __restrict__ bout,
                                                  float* __restrict__ outp) {
    __shared__ half_t As[2][128 * 32];
    __shared__ half_t Bs[2][128 * 32];
    int t = threadIdx.x;
    int w = t >> 6, l = t & 63, g = l >> 4, c = l & 15;
    int bid = blockIdx.x;                       // grid 784 = 8 * 98
    int logical = (bid & 7) * 98 + (bid >> 3);
    int mtile = logical & 1;                    // 2 x 128 oc
    int rest = logical >> 1;                    // 0..391
    int n0 = (rest % 98) * 128;
    int b = rest / 98;

    const half_t* Agl = Wout16 + (size_t)(mtile * 128) * 32;           // +kk*8192
    const half_t* Bgl = otok16 + ((size_t)b * 16 * HW + n0) * 32;      // +kk*401408

    int lrow = l >> 2, lj = l & 3;
    auto stage = [&](int buf, int kk) {
        #pragma unroll
        for (int i = 0; i < 2; ++i) {
            int row = w * 32 + i * 16 + lrow;
            int gs = lj ^ ((row >> 1) & 3);
            const half_t* sa = Agl + (size_t)kk * 8192 + (size_t)row * 32 + gs * 8;
            const half_t* sb = Bgl + (size_t)kk * 401408 + (size_t)row * 32 + gs * 8;
            half_t* da = &As[buf][(w * 32 + i * 16) * 32];
            half_t* db = &Bs[buf][(w * 32 + i * 16) * 32];
            __builtin_amdgcn_global_load_lds(
                (const __attribute__((address_space(1))) void*)sa,
                (__attribute__((address_space(3))) void*)da, 16, 0, 0);
            __builtin_amdgcn_global_load_lds(
                (const __attribute__((address_space(1))) void*)sb,
                (__attribute__((address_space(3))) void*)db, 16, 0, 0);
        }
    };

    stage(0, 0);
    __syncthreads();

    f32x4 sc[4][4];
    #pragma unroll
    for (int a = 0; a < 4; ++a)
        #pragma unroll
        for (int nt = 0; nt < 4; ++nt) sc[a][nt] = (f32x4){0.f, 0.f, 0.f, 0.f};

    int qm = w >> 1, qn = w & 1;
    int rsw = (c >> 1) & 3;

    for (int kk = 0; kk < 16; ++kk) {
        int cur = kk & 1;
        if (kk + 1 < 16) stage(cur ^ 1, kk + 1);
        half8 af[4], bf[4];
        #pragma unroll
        for (int a = 0; a < 4; ++a) {
            int row = qm * 64 + a * 16 + c;
            af[a] = *(const half8*)&As[cur][row * 32 + ((g ^ rsw) << 3)];
        }
        #pragma unroll
        for (int nt = 0; nt < 4; ++nt) {
            int row = qn * 64 + nt * 16 + c;
            bf[nt] = *(const half8*)&Bs[cur][row * 32 + ((g ^ rsw) << 3)];
        }
        __builtin_amdgcn_s_setprio(1);
        #pragma unroll
        for (int a = 0; a < 4; ++a)
            #pragma unroll
            for (int nt = 0; nt < 4; ++nt)
                sc[a][nt] = __builtin_amdgcn_mfma_f32_16x16x32_f16(af[a], bf[nt], sc[a][nt], 0, 0, 0);
        __builtin_amdgcn_s_setprio(0);
        __syncthreads();
    }
    #pragma unroll
    for (int a = 0; a < 4; ++a) {
        int ocb = mtile * 128 + qm * 64 + a * 16 + g * 4;
        float b0 = bout[ocb], b1 = bout[ocb + 1], b2 = bout[ocb + 2], b3 = bout[ocb + 3];
        float* op = outp + ((size_t)b * DIM + ocb) * HW + n0 + qn * 64 + c;
        #pragma unroll
        for (int nt = 0; nt < 4; ++nt) {
            op[(size_t)0 * HW + nt * 16] = sc[a][nt][0] + b0;
            op[(size_t)1 * HW + nt * 16] = sc[a][nt][1] + b1;
            op[(size_t)2 * HW + nt * 16] = sc[a][nt][2] + b2;
            op[(size_t)3 * HW + nt * 16] = sc[a][nt][3] + b3;
        }
    }
}

extern "C" void kernel_launch(void* const* d_in, const int* in_sizes, int n_in,
                              void* d_out, int out_size, void* d_ws, size_t ws_size,
                              hipStream_t stream) {
    (void)in_sizes; (void)n_in; (void)out_size; (void)ws_size;
    const float* x = (const float*)d_in[0];
    const float* Wq = (const float*)d_in[1];
    const float* Wkv = (const float*)d_in[2];
    const float* Wout = (const float*)d_in[3];
    const float* bout = (const float*)d_in[4];
    float* outp = (float*)d_out;

    // Workspace layout (f32 units; partial 8 slices = 8,388,608 floats):
    //   partial f32 [0, 8,388,608)                    (dead after k2r)
    //   kimg  bytes [14,680,064, 14,942,208)          (1MB: 32 bh x 32KB LDS image)
    //   vimg  bytes [14,942,208, 15,204,352)          (1MB, permuted+swizzled)
    //   Wq16s  f16  [15,204,352, 15,269,888)          (frag-ready, QSCALE2 folded)
    //   Wout16 f16  [15,269,888, 15,335,424)          (frag-ready)
    //   Wkv16  f16  [15,335,424, 21,757,952)          (frag-ready, dead after k_mid)
    //   Pt     f16  [21,757,952, 28,180,480)          (frag-ready, dead after k_mid)
    //   otok16 f16  [15,335,424, 28,180,480)          (frag-ready, overlays Wkv16+Pt)
    //   xT16   f16  [28,180,480, 34,603,008)          (frag-ready, dead after k_mid)
    //   qtok   f16  [34,603,008, 47,448,064)
    float* ws = (float*)d_ws;
    float*  partial = ws;
    char*   kimg    = (char*)(ws + 14680064);
    char*   vimg    = (char*)(ws + 14942208);
    half_t* Wq16s   = (half_t*)(ws + 15204352);
    half_t* Wout16  = (half_t*)(ws + 15269888);
    half_t* Wkv16   = (half_t*)(ws + 15335424);
    half_t* Pt      = (half_t*)(ws + 21757952);
    half_t* otok16  = (half_t*)(ws + 15335424);
    half_t* xT16    = (half_t*)(ws + 28180480);
    half_t* qtok    = (half_t*)(ws + 34603008);

    hipFuncSetAttribute((const void*)k3_attn,
                        hipFuncAttributeMaxDynamicSharedMemorySize, 65536);

    k_front<<<dim3(15808), 256, 0, stream>>>(x, Wkv, Wq, Wout,
                                             Wkv16, Wq16s, Wout16, Pt, xT16);
    k_mid<<<dim3(2080), 256, 0, stream>>>(Wkv16, Pt, partial, Wq16s, xT16, qtok);
    k2r<<<dim3(128, 4), 256, 0, stream>>>(partial, kimg, vimg);
    k3_attn<<<dim3(98, 32), 512, 65536, stream>>>(qtok, kimg, vimg, otok16);
    k4_outproj<<<dim3(784), 256, 0, stream>>>(Wout16, otok16, bout, outp);
}

// Round 21
// 165.321 us; speedup vs baseline: 1.3656x; 1.1555x over previous
//
#include <hip/hip_runtime.h>

#define HEADS 8
#define DHEAD 64
#define QSCALE 0.125f        // 64^-0.5
#define QSCALE2 0.1803368801111204f  // QSCALE * log2(e): exp2-direct softmax
#define DIM 256
#define IMG 112
#define HW 12544        // 112*112
#define NKV 256         // 16*16
#define INNER 512
#define KCONV 12544     // 256*49
#define KSPLIT 8
#define K2STEPS 49      // 392/8 kk'-chunks per split

typedef _Float16 half_t;
typedef _Float16 half8 __attribute__((ext_vector_type(8)));
typedef float f32x4 __attribute__((ext_vector_type(4)));

__device__ inline unsigned pk2(float a, float b) {
    union { half_t h[2]; unsigned u; } x;
    x.h[0] = (half_t)a; x.h[1] = (half_t)b;
    return x.u;
}

// ---------------- K_front: Wkv cvt (k'-major), Wq/Wout cvt, x transpose. One launch.
// grid 7360: [0,4096) Wkv k'-cvt, [4096,4160) Wq, [4160,4224) Wout, [4224,7360) transpose.
// K-reorder: k' = tap*256 + c  =>  Pt becomes xT16 itself (gather deleted).
__global__ __launch_bounds__(256) void k_front(const float* __restrict__ x,
                                               const float* __restrict__ Wkv,
                                               const float* __restrict__ Wq,
                                               const float* __restrict__ Wout,
                                               half_t* __restrict__ Wkv16,
                                               half_t* __restrict__ Wq16s,
                                               half_t* __restrict__ Wout16,
                                               half_t* __restrict__ xT16) {
    __shared__ float shmem[64 * 68];
    int bid = blockIdx.x;
    int t = threadIdx.x;
    if (bid < 4096) {
        // Wkv f32 [1024][c*49+tap] -> f16 [kk'=tap*8+(c>>5)][1024 oc][slot][8]
        int oc = bid >> 2;
        int cb = (bid & 3) * 64;
        const float* src = Wkv + (size_t)oc * KCONV + (size_t)cb * 49;
        #pragma unroll
        for (int i = 0; i < 13; ++i) {
            int idx = t + i * 256;
            if (idx < 3136) shmem[idx] = src[idx];
        }
        __syncthreads();
        #pragma unroll
        for (int it = 0; it < 2; ++it) {
            int gi = t + it * 256;
            if (gi < 392) {
                int tap = gi >> 3, oct = gi & 7;
                int cl = oct * 8;
                half8 h;
                #pragma unroll
                for (int e = 0; e < 8; ++e) h[e] = (half_t)shmem[(cl + e) * 49 + tap];
                int cglob = cb + cl;
                int kkp = tap * 8 + (cglob >> 5);
                int slot = (cglob >> 3) & 3;
                *(half8*)&Wkv16[((size_t)kkp * 1024 + oc) * 32 + slot * 8] = h;
            }
        }
    } else if (bid < 4224) {
        // Wq / Wout cvt (old frag-ready layout)
        const float* W;
        half_t* W16;
        float scale;
        int OC, K, gid;
        if (bid < 4160) {
            W = Wq; W16 = Wq16s; scale = QSCALE2; OC = 512; K = DIM;
            gid = (bid - 4096) * 256 + t;
        } else {
            W = Wout; W16 = Wout16; scale = 1.0f; OC = 256; K = INNER;
            gid = (bid - 4160) * 256 + t;
        }
        int perRow = K >> 3;
        int oc = gid / perRow;
        int k0 = (gid - oc * perRow) * 8;
        const float* src = W + (size_t)oc * K + k0;
        float4 a = *(const float4*)src;
        float4 b = *(const float4*)(src + 4);
        half8 h = { (half_t)(a.x * scale), (half_t)(a.y * scale),
                    (half_t)(a.z * scale), (half_t)(a.w * scale),
                    (half_t)(b.x * scale), (half_t)(b.y * scale),
                    (half_t)(b.z * scale), (half_t)(b.w * scale) };
        *(half8*)&W16[(((size_t)(k0 >> 5) * OC + oc) * 4 + ((k0 >> 3) & 3)) * 8] = h;
    } else {
        // x transpose -> x'[b][cg 8][n][slot][8]
        int idx = bid - 4224;
        int n0 = (idx % 196) * 64;
        int c0 = ((idx / 196) & 3) * 64;
        int b = idx / 784;
        #pragma unroll
        for (int i = 0; i < 4; ++i) {
            int f4 = t + i * 256;
            int r = f4 >> 4, c4 = (f4 & 15) << 2;
            *(float4*)&shmem[r * 68 + c4] =
                *(const float4*)&x[((size_t)(b * DIM + c0 + r)) * HW + n0 + c4];
        }
        __syncthreads();
        #pragma unroll
        for (int i = 0; i < 2; ++i) {
            int idx2 = t + i * 256;
            int rr = idx2 >> 3, cc8 = (idx2 & 7) << 3;
            half8 h;
            #pragma unroll
            for (int j = 0; j < 8; ++j) h[j] = (half_t)shmem[(cc8 + j) * 68 + rr];
            int ch = c0 + cc8;
            *(half8*)&xT16[((((size_t)b * 8 + (ch >> 5)) * HW + n0 + rr) * 4 + ((ch >> 3) & 3)) * 8] = h;
        }
    }
}

// ---------------- K_mid: k2 (KV conv GEMM, k'-order, B from xT16) + k1 (Q proj).
// grid 2080: [0,512) k2; [512,2080) k1. m97 template, 128x128 tile, gload_lds dbuf.
__global__ __launch_bounds__(256) void k_mid(const half_t* __restrict__ Wkv16,
                                             float* __restrict__ partial,
                                             const half_t* __restrict__ Wq16s,
                                             const half_t* __restrict__ xT16,
                                             half_t* __restrict__ qtok) {
    __shared__ half_t As[2][128 * 32];
    __shared__ half_t Bs[2][128 * 32];
    int t = threadIdx.x;
    int w = t >> 6, l = t & 63, g = l >> 4, c = l & 15;
    int lrow = l >> 2, lj = l & 3;
    int qm = w >> 1, qn = w & 1;
    int rsw = (c >> 1) & 3;
    int bid = blockIdx.x;

    if (bid < 512) {
        // ---- k2 body (B staged from xT16 via pixel addressing) ----
        int logical = (bid & 7) * 64 + (bid >> 3);
        int mtile = logical & 7;
        int rest = logical >> 3;
        int ntile = rest & 1;
        int grp = rest >> 1;                    // = ks*4 + b
        int ks = grp >> 2;
        int b = grp & 3;

        const half_t* Agl = Wkv16 + ((size_t)(ks * 49) * 1024 + mtile * 128) * 32;
        const half_t* xbase = xT16 + (size_t)b * 8 * HW * 32;

        // lane-const pixel bases + swizzled granule offsets for the 2 stage rows
        int pos0 = ntile * 128 + w * 32 + lrow;
        int pos1 = pos0 + 16;
        int row0 = w * 32 + lrow, row1 = row0 + 16;
        int gs0 = lj ^ ((row0 >> 1) & 3), gs1 = lj ^ ((row1 >> 1) & 3);
        size_t lb0 = (size_t)((pos0 >> 4) * 784 + (pos0 & 15) * 7) * 32 + gs0 * 8;
        size_t lb1 = (size_t)((pos1 >> 4) * 784 + (pos1 & 15) * 7) * 32 + gs1 * 8;

        auto stage = [&](int buf, int kk) {
            int kkg = ks * 49 + kk;
            int tap = kkg >> 3, cg = kkg & 7;
            int kh = tap / 7;
            size_t scal = ((size_t)cg * HW + (size_t)(kh * 112 + (tap - kh * 7))) * 32;
            {
                const half_t* sa = Agl + (size_t)kk * 32768 + (size_t)row0 * 32 + gs0 * 8;
                const half_t* sb = xbase + scal + lb0;
                __builtin_amdgcn_global_load_lds(
                    (const __attribute__((address_space(1))) void*)sa,
                    (__attribute__((address_space(3))) void*)&As[buf][(w * 32) * 32], 16, 0, 0);
                __builtin_amdgcn_global_load_lds(
                    (const __attribute__((address_space(1))) void*)sb,
                    (__attribute__((address_space(3))) void*)&Bs[buf][(w * 32) * 32], 16, 0, 0);
            }
            {
                const half_t* sa = Agl + (size_t)kk * 32768 + (size_t)row1 * 32 + gs1 * 8;
                const half_t* sb = xbase + scal + lb1;
                __builtin_amdgcn_global_load_lds(
                    (const __attribute__((address_space(1))) void*)sa,
                    (__attribute__((address_space(3))) void*)&As[buf][(w * 32 + 16) * 32], 16, 0, 0);
                __builtin_amdgcn_global_load_lds(
                    (const __attribute__((address_space(1))) void*)sb,
                    (__attribute__((address_space(3))) void*)&Bs[buf][(w * 32 + 16) * 32], 16, 0, 0);
            }
        };

        stage(0, 0);
        __syncthreads();

        f32x4 sc[4][4];
        #pragma unroll
        for (int a = 0; a < 4; ++a)
            #pragma unroll
            for (int nt = 0; nt < 4; ++nt) sc[a][nt] = (f32x4){0.f, 0.f, 0.f, 0.f};

        for (int kk = 0; kk < K2STEPS; ++kk) {
            int cur = kk & 1;
            if (kk + 1 < K2STEPS) stage(cur ^ 1, kk + 1);
            half8 af[4], bf[4];
            #pragma unroll
            for (int a = 0; a < 4; ++a) {
                int row = qm * 64 + a * 16 + c;
                af[a] = *(const half8*)&As[cur][row * 32 + ((g ^ rsw) << 3)];
            }
            #pragma unroll
            for (int nt = 0; nt < 4; ++nt) {
                int row = qn * 64 + nt * 16 + c;
                bf[nt] = *(const half8*)&Bs[cur][row * 32 + ((g ^ rsw) << 3)];
            }
            __builtin_amdgcn_s_setprio(1);
            #pragma unroll
            for (int a = 0; a < 4; ++a)
                #pragma unroll
                for (int nt = 0; nt < 4; ++nt)
                    sc[a][nt] = __builtin_amdgcn_mfma_f32_16x16x32_f16(af[a], bf[nt], sc[a][nt], 0, 0, 0);
            __builtin_amdgcn_s_setprio(0);
            __syncthreads();
        }
        float* op = partial + ((size_t)grp * 1024 + mtile * 128 + qm * 64 + g * 4) * 256
                    + ntile * 128 + qn * 64 + c;
        #pragma unroll
        for (int a = 0; a < 4; ++a)
            #pragma unroll
            for (int nt = 0; nt < 4; ++nt)
                #pragma unroll
                for (int r = 0; r < 4; ++r)
                    op[(size_t)(a * 16 + r) * 256 + nt * 16] = sc[a][nt][r];
    } else {
        // ---- k1 body (unchanged) ----
        int bl = bid - 512;                     // [0,1568)
        int logical = (bl & 7) * 196 + (bl >> 3);
        int mtile = logical & 3;
        int rest = logical >> 2;
        int n0 = (rest % 98) * 128;
        int b = rest / 98;

        const half_t* Agl = Wq16s + (size_t)(mtile * 128) * 32;
        const half_t* Bgl = xT16 + ((size_t)b * 8 * HW + n0) * 32;

        auto stage = [&](int buf, int kk) {
            #pragma unroll
            for (int i = 0; i < 2; ++i) {
                int row = w * 32 + i * 16 + lrow;
                int gs = lj ^ ((row >> 1) & 3);
                const half_t* sa = Agl + (size_t)kk * 16384 + (size_t)row * 32 + gs * 8;
                const half_t* sb = Bgl + (size_t)kk * 401408 + (size_t)row * 32 + gs * 8;
                half_t* da = &As[buf][(w * 32 + i * 16) * 32];
                half_t* db = &Bs[buf][(w * 32 + i * 16) * 32];
                __builtin_amdgcn_global_load_lds(
                    (const __attribute__((address_space(1))) void*)sa,
                    (__attribute__((address_space(3))) void*)da, 16, 0, 0);
                __builtin_amdgcn_global_load_lds(
                    (const __attribute__((address_space(1))) void*)sb,
                    (__attribute__((address_space(3))) void*)db, 16, 0, 0);
            }
        };

        stage(0, 0);
        __syncthreads();

        f32x4 sc[4][4];
        #pragma unroll
        for (int a = 0; a < 4; ++a)
            #pragma unroll
            for (int nt = 0; nt < 4; ++nt) sc[a][nt] = (f32x4){0.f, 0.f, 0.f, 0.f};

        for (int kk = 0; kk < 8; ++kk) {
            int cur = kk & 1;
            if (kk + 1 < 8) stage(cur ^ 1, kk + 1);
            half8 af[4], bf[4];
            #pragma unroll
            for (int a = 0; a < 4; ++a) {
                int row = qm * 64 + a * 16 + c;
                af[a] = *(const half8*)&As[cur][row * 32 + ((g ^ rsw) << 3)];
            }
            #pragma unroll
            for (int nt = 0; nt < 4; ++nt) {
                int row = qn * 64 + nt * 16 + c;
                bf[nt] = *(const half8*)&Bs[cur][row * 32 + ((g ^ rsw) << 3)];
            }
            __builtin_amdgcn_s_setprio(1);
            #pragma unroll
            for (int a = 0; a < 4; ++a)
                #pragma unroll
                for (int nt = 0; nt < 4; ++nt)
                    sc[a][nt] = __builtin_amdgcn_mfma_f32_16x16x32_f16(af[a], bf[nt], sc[a][nt], 0, 0, 0);
            __builtin_amdgcn_s_setprio(0);
            __syncthreads();
        }
        int h = mtile * 2 + qm;
        half_t* op = qtok + ((size_t)(b * HEADS + h) * HW + n0 + qn * 64 + c) * 64 + g * 4;
        #pragma unroll
        for (int a = 0; a < 4; ++a)
            #pragma unroll
            for (int nt = 0; nt < 4; ++nt) {
                uint2 u = make_uint2(pk2(sc[a][nt][0], sc[a][nt][1]),
                                     pk2(sc[a][nt][2], sc[a][nt][3]));
                *(uint2*)&op[(size_t)(nt * 16) * 64 + a * 16] = u;
            }
    }
}

// ---------------- K2r: reduce partials -> PRE-SWIZZLED LDS images for k3 (unchanged)
__global__ __launch_bounds__(256) void k2r(const float* __restrict__ partial,
                                           char* __restrict__ kimg,
                                           char* __restrict__ vimg) {
    int pos = threadIdx.x;
    int oc0 = blockIdx.x * 8;
    int b = blockIdx.y;
    float v[8];
    #pragma unroll
    for (int j = 0; j < 8; ++j) {
        const float* src = partial + ((size_t)b * 1024 + oc0 + j) * 256 + pos;
        float s = 0.f;
        #pragma unroll
        for (int ksb = 0; ksb < KSPLIT; ++ksb) s += src[(size_t)ksb * 1048576];
        v[j] = s;
    }
    int h = (oc0 >> 6) & 7, d0 = oc0 & 63;
    if (oc0 < 512) {
        uint4 u = make_uint4(pk2(v[0], v[1]), pk2(v[2], v[3]),
                             pk2(v[4], v[5]), pk2(v[6], v[7]));
        size_t off = ((size_t)(b * HEADS + h) << 15) + pos * 128
                     + (((unsigned)(d0 * 2)) ^ ((unsigned)((pos & 7) << 4)));
        *(uint4*)(kimg + off) = u;
    } else {
        int posP = (pos & ~31) | (((pos >> 2) & 3) << 3) | (((pos >> 4) & 1) << 2) | (pos & 3);
        size_t base = ((size_t)(b * HEADS + h) << 15);
        #pragma unroll
        for (int j = 0; j < 8; ++j) {
            int d = d0 + j;
            size_t off = base + d * 512
                         + ((((unsigned)(posP >> 3) << 4)) ^ ((unsigned)((d & 7) << 4)))
                         + (posP & 7) * 2;
            *(half_t*)(vimg + off) = (half_t)v[j];
        }
    }
}

// ---------------- K3: fused attention (unchanged)
__global__ __launch_bounds__(512) void k3_attn(const half_t* __restrict__ qtok,
                                               const char* __restrict__ kimg,
                                               const char* __restrict__ vimg,
                                               half_t* __restrict__ otok16) {
    extern __shared__ char lds[];
    char* K_lds = lds;
    char* V_lds = lds + 32768;
    int t = threadIdx.x;
    int w = t >> 6, l = t & 63, g = l >> 4, c = l & 15;
    int q0 = blockIdx.x * 128;
    int bh = blockIdx.y;

    const half_t* qp = qtok + ((size_t)bh * HW + q0 + w * 16 + c) * 64 + g * 8;
    half8 bq0 = *(const half8*)(qp);
    half8 bq1 = *(const half8*)(qp + 32);

    {
        const char* ksrc = kimg + ((size_t)bh << 15);
        const char* vsrc = vimg + ((size_t)bh << 15);
        int l16 = l * 16;
        #pragma unroll
        for (int j = 0; j < 4; ++j) {
            int off = (j * 8 + w) * 1024;
            __builtin_amdgcn_global_load_lds(
                (const __attribute__((address_space(1))) void*)(ksrc + off + l16),
                (__attribute__((address_space(3))) void*)(K_lds + off), 16, 0, 0);
            __builtin_amdgcn_global_load_lds(
                (const __attribute__((address_space(1))) void*)(vsrc + off + l16),
                (__attribute__((address_space(3))) void*)(V_lds + off), 16, 0, 0);
        }
    }
    __syncthreads();

    f32x4 sc[16];
    __builtin_amdgcn_s_setprio(1);
    #pragma unroll
    for (int nt = 0; nt < 16; ++nt) {
        int row = nt * 16 + c;
        const char* kp = K_lds + row * 128;
        unsigned sw = (unsigned)((row & 7) << 4);
        half8 a0 = *(const half8*)(kp + (((unsigned)(g * 16)) ^ sw));
        half8 a1 = *(const half8*)(kp + (((unsigned)(g * 16 + 64)) ^ sw));
        f32x4 acc = (f32x4){0.f, 0.f, 0.f, 0.f};
        acc = __builtin_amdgcn_mfma_f32_16x16x32_f16(a0, bq0, acc, 0, 0, 0);
        acc = __builtin_amdgcn_mfma_f32_16x16x32_f16(a1, bq1, acc, 0, 0, 0);
        sc[nt] = acc;
    }
    __builtin_amdgcn_s_setprio(0);

    float s = 0.f;
    #pragma unroll
    for (int nt = 0; nt < 16; ++nt)
        #pragma unroll
        for (int r = 0; r < 4; ++r) {
            float e = __builtin_amdgcn_exp2f(sc[nt][r]);
            sc[nt][r] = e;
            s += e;
        }
    s += __shfl_xor(s, 16);
    s += __shfl_xor(s, 32);
    float inv = 1.f / s;

    f32x4 o[4];
    #pragma unroll
    for (int nt = 0; nt < 4; ++nt) o[nt] = (f32x4){0.f, 0.f, 0.f, 0.f};
    __builtin_amdgcn_s_setprio(1);
    #pragma unroll
    for (int ks = 0; ks < 8; ++ks) {
        union { unsigned u[4]; half8 h; } ap;
        ap.u[0] = pk2(sc[2 * ks][0], sc[2 * ks][1]);
        ap.u[1] = pk2(sc[2 * ks][2], sc[2 * ks][3]);
        ap.u[2] = pk2(sc[2 * ks + 1][0], sc[2 * ks + 1][1]);
        ap.u[3] = pk2(sc[2 * ks + 1][2], sc[2 * ks + 1][3]);
        #pragma unroll
        for (int dt = 0; dt < 4; ++dt) {
            int d = dt * 16 + c;
            half8 av = *(const half8*)(V_lds + d * 512 +
                                       (((unsigned)(ks * 64 + g * 16)) ^ ((unsigned)((d & 7) << 4))));
            o[dt] = __builtin_amdgcn_mfma_f32_16x16x32_f16(av, ap.h, o[dt], 0, 0, 0);
        }
    }
    __builtin_amdgcn_s_setprio(0);
    int b = bh >> 3, h = bh & 7;
    #pragma unroll
    for (int dt = 0; dt < 4; ++dt) {
        uint2 u = make_uint2(pk2(o[dt][0] * inv, o[dt][1] * inv),
                             pk2(o[dt][2] * inv, o[dt][3] * inv));
        size_t off = (((size_t)b * 16 + h * 2 + (dt >> 1)) * HW + q0 + w * 16 + c) * 32
                     + (size_t)(((dt & 1) * 2 + (g >> 1)) * 8 + (g & 1) * 4);
        *(uint2*)&otok16[off] = u;
    }
}

// ---------------- K4: output projection + bias (unchanged)
__global__ __launch_bounds__(256) void k4_outproj(const half_t* __restrict__ Wout16,
                                                  const half_t* __restrict__ otok16,
                                                  const float* __restrict__ bout,
                                                  float* __restrict__ outp) {
    __shared__ half_t As[2][128 * 32];
    __shared__ half_t Bs[2][128 * 32];
    int t = threadIdx.x;
    int w = t >> 6, l = t & 63, g = l >> 4, c = l & 15;
    int bid = blockIdx.x;                       // grid 784 = 8 * 98
    int logical = (bid & 7) * 98 + (bid >> 3);
    int mtile = logical & 1;
    int rest = logical >> 1;
    int n0 = (rest % 98) * 128;
    int b = rest / 98;

    const half_t* Agl = Wout16 + (size_t)(mtile * 128) * 32;
    const half_t* Bgl = otok16 + ((size_t)b * 16 * HW + n0) * 32;

    int lrow = l >> 2, lj = l & 3;
    auto stage = [&](int buf, int kk) {
        #pragma unroll
        for (int i = 0; i < 2; ++i) {
            int row = w * 32 + i * 16 + lrow;
            int gs = lj ^ ((row >> 1) & 3);
            const half_t* sa = Agl + (size_t)kk * 8192 + (size_t)row * 32 + gs * 8;
            const half_t* sb = Bgl + (size_t)kk * 401408 + (size_t)row * 32 + gs * 8;
            half_t* da = &As[buf][(w * 32 + i * 16) * 32];
            half_t* db = &Bs[buf][(w * 32 + i * 16) * 32];
            __builtin_amdgcn_global_load_lds(
                (const __attribute__((address_space(1))) void*)sa,
                (__attribute__((address_space(3))) void*)da, 16, 0, 0);
            __builtin_amdgcn_global_load_lds(
                (const __attribute__((address_space(1))) void*)sb,
                (__attribute__((address_space(3))) void*)db, 16, 0, 0);
        }
    };

    stage(0, 0);
    __syncthreads();

    f32x4 sc[4][4];
    #pragma unroll
    for (int a = 0; a < 4; ++a)
        #pragma unroll
        for (int nt = 0; nt < 4; ++nt) sc[a][nt] = (f32x4){0.f, 0.f, 0.f, 0.f};

    int qm = w >> 1, qn = w & 1;
    int rsw = (c >> 1) & 3;

    for (int kk = 0; kk < 16; ++kk) {
        int cur = kk & 1;
        if (kk + 1 < 16) stage(cur ^ 1, kk + 1);
        half8 af[4], bf[4];
        #pragma unroll
        for (int a = 0; a < 4; ++a) {
            int row = qm * 64 + a * 16 + c;
            af[a] = *(const half8*)&As[cur][row * 32 + ((g ^ rsw) << 3)];
        }
        #pragma unroll
        for (int nt = 0; nt < 4; ++nt) {
            int row = qn * 64 + nt * 16 + c;
            bf[nt] = *(const half8*)&Bs[cur][row * 32 + ((g ^ rsw) << 3)];
        }
        __builtin_amdgcn_s_setprio(1);
        #pragma unroll
        for (int a = 0; a < 4; ++a)
            #pragma unroll
            for (int nt = 0; nt < 4; ++nt)
                sc[a][nt] = __builtin_amdgcn_mfma_f32_16x16x32_f16(af[a], bf[nt], sc[a][nt], 0, 0, 0);
        __builtin_amdgcn_s_setprio(0);
        __syncthreads();
    }
    #pragma unroll
    for (int a = 0; a < 4; ++a) {
        int ocb = mtile * 128 + qm * 64 + a * 16 + g * 4;
        float b0 = bout[ocb], b1 = bout[ocb + 1], b2 = bout[ocb + 2], b3 = bout[ocb + 3];
        float* op = outp + ((size_t)b * DIM + ocb) * HW + n0 + qn * 64 + c;
        #pragma unroll
        for (int nt = 0; nt < 4; ++nt) {
            op[(size_t)0 * HW + nt * 16] = sc[a][nt][0] + b0;
            op[(size_t)1 * HW + nt * 16] = sc[a][nt][1] + b1;
            op[(size_t)2 * HW + nt * 16] = sc[a][nt][2] + b2;
            op[(size_t)3 * HW + nt * 16] = sc[a][nt][3] + b3;
        }
    }
}

extern "C" void kernel_launch(void* const* d_in, const int* in_sizes, int n_in,
                              void* d_out, int out_size, void* d_ws, size_t ws_size,
                              hipStream_t stream) {
    (void)in_sizes; (void)n_in; (void)out_size; (void)ws_size;
    const float* x = (const float*)d_in[0];
    const float* Wq = (const float*)d_in[1];
    const float* Wkv = (const float*)d_in[2];
    const float* Wout = (const float*)d_in[3];
    const float* bout = (const float*)d_in[4];
    float* outp = (float*)d_out;

    // Workspace layout (f32 units; partial 8 slices = 8,388,608 floats):
    //   partial f32 [0, 8,388,608)                    (dead after k2r)
    //   kimg  bytes [14,680,064, 14,942,208)          (1MB: 32 bh x 32KB LDS image)
    //   vimg  bytes [14,942,208, 15,204,352)          (1MB, permuted+swizzled)
    //   Wq16s  f16  [15,204,352, 15,269,888)          (frag-ready, QSCALE2 folded)
    //   Wout16 f16  [15,269,888, 15,335,424)          (frag-ready)
    //   Wkv16  f16  [15,335,424, 21,757,952)          (k'-major frag-ready, dead after k_mid)
    //   otok16 f16  [15,335,424, 28,180,480)          (overlays Wkv16+old Pt region)
    //   xT16   f16  [28,180,480, 34,603,008)          (dead after k_mid)
    //   qtok   f16  [34,603,008, 47,448,064)
    float* ws = (float*)d_ws;
    float*  partial = ws;
    char*   kimg    = (char*)(ws + 14680064);
    char*   vimg    = (char*)(ws + 14942208);
    half_t* Wq16s   = (half_t*)(ws + 15204352);
    half_t* Wout16  = (half_t*)(ws + 15269888);
    half_t* Wkv16   = (half_t*)(ws + 15335424);
    half_t* otok16  = (half_t*)(ws + 15335424);
    half_t* xT16    = (half_t*)(ws + 28180480);
    half_t* qtok    = (half_t*)(ws + 34603008);

    hipFuncSetAttribute((const void*)k3_attn,
                        hipFuncAttributeMaxDynamicSharedMemorySize, 65536);

    k_front<<<dim3(7360), 256, 0, stream>>>(x, Wkv, Wq, Wout,
                                            Wkv16, Wq16s, Wout16, xT16);
    k_mid<<<dim3(2080), 256, 0, stream>>>(Wkv16, partial, Wq16s, xT16, qtok);
    k2r<<<dim3(128, 4), 256, 0, stream>>>(partial, kimg, vimg);
    k3_attn<<<dim3(98, 32), 512, 65536, stream>>>(qtok, kimg, vimg, otok16);
    k4_outproj<<<dim3(784), 256, 0, stream>>>(Wout16, otok16, bout, outp);
}